// Round 14
// baseline (1279.473 us; speedup 1.0000x reference)
//
#include <hip/hip_runtime.h>

typedef short s8v __attribute__((ext_vector_type(8)));
typedef float f32x4 __attribute__((ext_vector_type(4)));

#define OBS_T 8
#define NSTEPS 20

__device__ __forceinline__ unsigned short f2bf(float x) {
    unsigned u = __float_as_uint(x);
    u = (u + 0x7FFFu + ((u >> 16) & 1u)) >> 16;
    return (unsigned short)u;
}
__device__ __forceinline__ float bf2f(unsigned short h) {
    return __uint_as_float(((unsigned)h) << 16);
}
__device__ __forceinline__ void store2(unsigned short* H, unsigned short* M,
                                       int ci, float v) {
    unsigned short h = f2bf(v);
    H[ci] = h; M[ci] = f2bf(v - bf2f(h));
}

// ---------------- prep: pack x2-split bf16 weight fragments (unchanged) ----------------
__global__ void slstm_prep(const float* __restrict__ Wp,
                           const float* __restrict__ Wi, const float* __restrict__ Wf,
                           const float* __restrict__ Wo, const float* __restrict__ Wg,
                           unsigned short* __restrict__ W4H, unsigned short* __restrict__ W4L,
                           unsigned short* __restrict__ WpH, unsigned short* __restrict__ WpL) {
    int x = blockIdx.x * blockDim.x + threadIdx.x;
    const int NW4 = 32 * 8 * 64 * 8;      // 131072
    const int NWP = 64 * 4 * 4 * 64 * 8;  // 524288
    if (x < NW4) {
        int j = x & 7, lane = (x >> 3) & 63, ks = (x >> 9) & 7, nt2 = x >> 12;
        int q = nt2 & 3, wvb = nt2 >> 2;
        int col = wvb * 16 + (lane & 15);
        int k = ks * 32 + ((lane >> 4) << 3) + j;
        const float* W = (q == 0) ? Wi : (q == 1) ? Wf : (q == 2) ? Wo : Wg;
        float v = W[k * 128 + col];
        unsigned short h = f2bf(v);
        W4H[x] = h; W4L[x] = f2bf(v - bf2f(h));
    } else if (x < NW4 + NWP) {
        int y = x - NW4;
        int j = y & 7, lane = (y >> 3) & 63, ks = (y >> 9) & 3, nt = (y >> 11) & 3, bin = y >> 13;
        int e = nt * 16 + (lane & 15);
        int k = ks * 32 + ((lane >> 4) << 3) + j;
        float v = Wp[(bin * 128 + k) * 64 + e];
        unsigned short h = f2bf(v);
        WpH[y] = h; WpL[y] = f2bf(v - bf2f(h));
    }
}

// ---------------- mono persistent kernel: 1 WG per sequence, Y via global (L2) ----------------
__global__ __launch_bounds__(512, 1) void slstm_mono(
    const float* __restrict__ obs_rel, const float* __restrict__ obs_abs,
    const float* __restrict__ We, const float* __restrict__ be,
    const float* __restrict__ bp,
    const float* __restrict__ bi, const float* __restrict__ bfv,
    const float* __restrict__ bo, const float* __restrict__ bg,
    const float* __restrict__ Wout, const float* __restrict__ bout,
    const unsigned short* __restrict__ W4H, const unsigned short* __restrict__ W4L,
    const unsigned short* __restrict__ WpH, const unsigned short* __restrict__ WpL,
    float* __restrict__ YG,
    float* __restrict__ out) {

    __shared__ __align__(16) unsigned short combH[32 * 256];
    __shared__ __align__(16) unsigned short combM[32 * 256];
    __shared__ __align__(16) float hbuf[32 * 128];
    __shared__ float posb[64];
    __shared__ float pvbuf[64];
    __shared__ float red[256];
    __shared__ unsigned char binTab[1024];
    __shared__ unsigned char usedList[64];
    __shared__ unsigned char binSlotL[64];
    __shared__ unsigned short glist[1024];
    __shared__ unsigned long long gstartPacked[32];
    __shared__ int nUsedS;
    __shared__ unsigned jneedS[64];
    __shared__ float biasL[512], beL[64], bpL[64], WeL[128], WoutL[256], boutL[2];

    const int tid = threadIdx.x;
    const int lane = tid & 63;
    const int wv = tid >> 6;
    const int b = blockIdx.x;
    float* Yb = YG + (size_t)b * 131072;   // 64 slots x 32 j x 64 e

    if (tid < 512) biasL[tid] = (tid < 128) ? bi[tid] : (tid < 256) ? bfv[tid - 128]
                              : (tid < 384) ? bo[tid - 256] : bg[tid - 384];
    if (tid < 64) { beL[tid] = be[tid]; bpL[tid] = bp[tid]; }
    if (tid < 128) WeL[tid] = We[tid];
    if (tid < 256) WoutL[tid] = Wout[tid];
    if (tid < 2) boutL[tid] = bout[tid];
    for (int x = tid; x < 32 * 256; x += 512) { combH[x] = 0; combM[x] = 0; }
    for (int x = tid; x < 32 * 128; x += 512) hbuf[x] = 0.f;
    float creg[8];
#pragma unroll
    for (int r = 0; r < 8; ++r) creg[r] = 0.f;
    __syncthreads();

    const float gnorm = (float)(2.0 / 7.0);
    const int gi = tid >> 4;
    const int gg = tid & 15;
    const int hc = wv * 16 + (lane & 15);
    const int j4 = (lane >> 4) << 2;

    for (int t = 0; t < NSTEPS; ++t) {
        // ---------- E_obs: positions + embedding ----------
        if (t < OBS_T) {
            if (tid < 64) posb[tid] = obs_abs[t * 2048 + b * 64 + tid];
            {
                int e0 = gg * 4;
                float x0 = obs_rel[t * 2048 + b * 64 + gi * 2];
                float x1 = obs_rel[t * 2048 + b * 64 + gi * 2 + 1];
#pragma unroll
                for (int r = 0; r < 4; ++r) {
                    int e = e0 + r;
                    float v = x0 * WeL[e] + x1 * WeL[64 + e] + beL[e];
                    store2(combH, combM, gi * 256 + (e ^ ((gi & 7) << 3)), v);
                }
            }
        }
        if (tid < 64) jneedS[tid] = 0u;
        __syncthreads();                       // B1

        float sreg[4] = {0.f, 0.f, 0.f, 0.f};
        if (t > 0) {
            // ---------- S0: bins ----------
#pragma unroll
            for (int pp = 0; pp < 2; ++pp) {
                int pr = tid + pp * 512;
                int i = pr >> 5, j = pr & 31;
                float rx = (posb[j * 2]     - posb[i * 2])     / gnorm;
                float ry = (posb[j * 2 + 1] - posb[i * 2 + 1]) / gnorm;
                rx = fminf(fmaxf(rx, -4.f), 4.f);
                ry = fminf(fmaxf(ry, -4.f), 4.f);
                int gx = (int)(rx + 4.f);
                int gy = (int)(ry + 4.f);
                int valid = (gx < 8) && (gy < 8) && (i != j);
                int bin = gy * 8 + gx;
                binTab[pr] = valid ? (unsigned char)bin : (unsigned char)255;
                if (valid) atomicOr(&jneedS[bin], 1u << j);
            }
            __syncthreads();                   // B2
            // ---------- S1: ballot compaction ----------
            if (wv == 0) {
                bool used = jneedS[lane] != 0u;
                unsigned long long bal = __ballot(used);
                int myIdx = __popcll(bal & ((1ull << lane) - 1ull));
                if (used) usedList[myIdx] = (unsigned char)lane;
                binSlotL[lane] = used ? (unsigned char)myIdx : (unsigned char)255;
                if (lane == 0) nUsedS = __popcll(bal);
            }
            __syncthreads();                   // B3
            const int nUsed = nUsedS;

            // A-frags: h rows (comb cols 64..191), both halves
            s8v Ahs[2][4], Ams[2][4];
#pragma unroll
            for (int m = 0; m < 2; ++m)
#pragma unroll
                for (int ks = 0; ks < 4; ++ks) {
                    int row = m * 16 + (lane & 15);
                    int k = ks * 32 + ((lane >> 4) << 3);
                    int ci = row * 256 + ((64 + k) ^ ((row & 7) << 3));
                    Ahs[m][ks] = *(const s8v*)&combH[ci];
                    Ams[m][ks] = *(const s8v*)&combM[ci];
                }

            // glist build (wave 0 lanes 0..31) — overlaps other waves' Y start
            if (tid < 32) {
                const int i = tid;
                unsigned rw[8];
#pragma unroll
                for (int w = 0; w < 8; ++w)
                    rw[w] = *(const unsigned*)&binTab[i * 32 + w * 4];
                unsigned long long cntp = 0;
#pragma unroll
                for (int j = 0; j < 32; ++j) {
                    unsigned bb = (rw[j >> 2] >> ((j & 3) * 8)) & 255u;
                    if (bb != 255u) cntp += 1ull << (5 * (binSlotL[bb] >> 3));
                }
                unsigned long long pre = 0; unsigned sum = 0;
#pragma unroll
                for (int c = 0; c < 8; ++c) {
                    pre |= (unsigned long long)sum << (5 * c);
                    sum += (unsigned)((cntp >> (5 * c)) & 31);
                }
                gstartPacked[i] = pre | ((unsigned long long)sum << 40);
                unsigned long long pos = pre;
#pragma unroll
                for (int j = 0; j < 32; ++j) {
                    unsigned bb = (rw[j >> 2] >> ((j & 3) * 8)) & 255u;
                    if (bb != 255u) {
                        int sg = binSlotL[bb];
                        int c = sg >> 3;
                        int pidx = (int)((pos >> (5 * c)) & 31);
                        glist[i * 32 + pidx] = (unsigned short)((sg << 5) | j);
                        pos += 1ull << (5 * c);
                    }
                }
            }

            // ---------- Y: barrier-free social GEMM to global (L2) ----------
            {
                const int np = wv & 1;
                for (int slot = (wv >> 1); slot < nUsed; slot += 4) {
                    int bin = usedList[slot];
                    unsigned need = jneedS[bin];
                    unsigned hm0 = need & 0xFFFFu, hm1 = need >> 16;
                    s8v bh0[4], bl0[4], bh1[4], bl1[4];
#pragma unroll
                    for (int ks = 0; ks < 4; ++ks) {
                        int foA = ((bin * 4 + np * 2)     * 4 + ks) * 64 + lane;
                        int foB = ((bin * 4 + np * 2 + 1) * 4 + ks) * 64 + lane;
                        bh0[ks] = ((const s8v*)WpH)[foA];
                        bl0[ks] = ((const s8v*)WpL)[foA];
                        bh1[ks] = ((const s8v*)WpH)[foB];
                        bl1[ks] = ((const s8v*)WpL)[foB];
                    }
#pragma unroll
                    for (int m = 0; m < 2; ++m) {
                        unsigned hm = m ? hm1 : hm0;
                        if (!hm) continue;
                        f32x4 a0 = {0.f, 0.f, 0.f, 0.f};
                        f32x4 a1 = {0.f, 0.f, 0.f, 0.f};
#pragma unroll
                        for (int ks = 0; ks < 4; ++ks) {
                            a0 = __builtin_amdgcn_mfma_f32_16x16x32_bf16(Ams[m][ks], bh0[ks], a0, 0, 0, 0);
                            a0 = __builtin_amdgcn_mfma_f32_16x16x32_bf16(Ahs[m][ks], bl0[ks], a0, 0, 0, 0);
                            a0 = __builtin_amdgcn_mfma_f32_16x16x32_bf16(Ahs[m][ks], bh0[ks], a0, 0, 0, 0);
                            a1 = __builtin_amdgcn_mfma_f32_16x16x32_bf16(Ams[m][ks], bh1[ks], a1, 0, 0, 0);
                            a1 = __builtin_amdgcn_mfma_f32_16x16x32_bf16(Ahs[m][ks], bl1[ks], a1, 0, 0, 0);
                            a1 = __builtin_amdgcn_mfma_f32_16x16x32_bf16(Ahs[m][ks], bh1[ks], a1, 0, 0, 0);
                        }
#pragma unroll
                        for (int nt = 0; nt < 2; ++nt) {
                            int e = (np * 2 + nt) * 16 + (lane & 15);
                            const f32x4 a = nt ? a1 : a0;
#pragma unroll
                            for (int r = 0; r < 4; ++r) {
                                if ((hm >> (j4 + r)) & 1u) {
                                    int j = m * 16 + j4 + r;
                                    Yb[(slot * 32 + j) * 64 + e] = a[r];
                                }
                            }
                        }
                    }
                }
            }
            __syncthreads();                   // B4: Y stores + glist visible

            // ---------- gather via glist (global-memory visibility per __syncthreads) ----------
            {
                const int e0 = gg * 4;
                const unsigned long long sp = gstartPacked[gi];
                const int cnt = (int)(sp >> 40);
                const unsigned short* gl = &glist[gi * 32];
                for (int p0 = 0; p0 < cnt; p0 += 4) {
                    unsigned long long e4 = *(const unsigned long long*)&gl[p0];
                    int n = cnt - p0;
                    unsigned en0 = (unsigned)(e4 & 0xFFFF), en1 = (unsigned)((e4 >> 16) & 0xFFFF);
                    unsigned en2 = (unsigned)((e4 >> 32) & 0xFFFF), en3 = (unsigned)((e4 >> 48) & 0xFFFF);
                    float4 y0, y1, y2, y3;
                    if (n > 0) y0 = *(const float4*)&Yb[(((en0 >> 5) * 32) + (en0 & 31)) * 64 + e0];
                    if (n > 1) y1 = *(const float4*)&Yb[(((en1 >> 5) * 32) + (en1 & 31)) * 64 + e0];
                    if (n > 2) y2 = *(const float4*)&Yb[(((en2 >> 5) * 32) + (en2 & 31)) * 64 + e0];
                    if (n > 3) y3 = *(const float4*)&Yb[(((en3 >> 5) * 32) + (en3 & 31)) * 64 + e0];
                    if (n > 0) { sreg[0] += y0.x; sreg[1] += y0.y; sreg[2] += y0.z; sreg[3] += y0.w; }
                    if (n > 1) { sreg[0] += y1.x; sreg[1] += y1.y; sreg[2] += y1.z; sreg[3] += y1.w; }
                    if (n > 2) { sreg[0] += y2.x; sreg[1] += y2.y; sreg[2] += y2.z; sreg[3] += y2.w; }
                    if (n > 3) { sreg[0] += y3.x; sreg[1] += y3.y; sreg[2] += y3.z; sreg[3] += y3.w; }
                }
            }
        }

        // finalize s = relu(pooled + bp) -> comb cols 192..255
        {
            int e0 = gg * 4;
#pragma unroll
            for (int r = 0; r < 4; ++r) {
                float v = fmaxf(sreg[r] + bpL[e0 + r], 0.f);
                store2(combH, combM, gi * 256 + ((192 + e0 + r) ^ ((gi & 7) << 3)), v);
            }
        }

        // ---------- E_pred ----------
        if (t >= OBS_T) {
            if (tid < 256) {
                int i = tid >> 3, d = (tid >> 2) & 1, pp = tid & 3;
                float acc = 0.f;
                int k0 = pp * 32;
                for (int k = k0; k < k0 + 32; ++k)
                    acc += hbuf[i * 128 + (k ^ ((i & 7) << 2))] * WoutL[k * 2 + d];
                red[tid] = acc;
            }
            __syncthreads();                   // B5
            if (tid < 64) {
                int d = tid & 1;
                float pv = red[tid * 4] + red[tid * 4 + 1] + red[tid * 4 + 2] + red[tid * 4 + 3]
                         + boutL[d];
                out[(t - OBS_T) * 2048 + b * 64 + tid] = pv;
                posb[tid] += pv;
                pvbuf[tid] = pv;
            }
            __syncthreads();                   // B6
            {
                int e0 = gg * 4;
                float x0 = pvbuf[gi * 2], x1 = pvbuf[gi * 2 + 1];
#pragma unroll
                for (int r = 0; r < 4; ++r) {
                    int e = e0 + r;
                    float v = x0 * WeL[e] + x1 * WeL[64 + e] + beL[e];
                    store2(combH, combM, gi * 256 + (e ^ ((gi & 7) << 3)), v);
                }
            }
        }
        __syncthreads();                       // B7: comb complete

        // ---------- G: gates (bf16x2 MFMA, ks-prefetched; r7 verbatim) ----------
        {
            f32x4 acc[4][2];
            f32x4 zero = {0.f, 0.f, 0.f, 0.f};
#pragma unroll
            for (int q = 0; q < 4; ++q) { acc[q][0] = zero; acc[q][1] = zero; }
            s8v gbh[2][4], gbl[2][4];
#pragma unroll
            for (int q = 0; q < 4; ++q) {
                int fo = ((wv * 4 + q) * 8 + 0) * 64 + lane;
                gbh[0][q] = ((const s8v*)W4H)[fo];
                gbl[0][q] = ((const s8v*)W4L)[fo];
            }
#pragma unroll
            for (int ks = 0; ks < 8; ++ks) {
                const int cb = ks & 1;
                if (ks < 7) {
#pragma unroll
                    for (int q = 0; q < 4; ++q) {
                        int fo = ((wv * 4 + q) * 8 + ks + 1) * 64 + lane;
                        gbh[cb ^ 1][q] = ((const s8v*)W4H)[fo];
                        gbl[cb ^ 1][q] = ((const s8v*)W4L)[fo];
                    }
                }
                s8v Ah[2], Am[2];
#pragma unroll
                for (int m = 0; m < 2; ++m) {
                    int row = m * 16 + (lane & 15);
                    int k = ks * 32 + ((lane >> 4) << 3);
                    int ci = row * 256 + (k ^ ((row & 7) << 3));
                    Ah[m] = *(const s8v*)&combH[ci];
                    Am[m] = *(const s8v*)&combM[ci];
                }
#pragma unroll
                for (int q = 0; q < 4; ++q)
#pragma unroll
                    for (int m = 0; m < 2; ++m) {
                        acc[q][m] = __builtin_amdgcn_mfma_f32_16x16x32_bf16(Am[m], gbh[cb][q], acc[q][m], 0, 0, 0);
                        acc[q][m] = __builtin_amdgcn_mfma_f32_16x16x32_bf16(Ah[m], gbl[cb][q], acc[q][m], 0, 0, 0);
                        acc[q][m] = __builtin_amdgcn_mfma_f32_16x16x32_bf16(Ah[m], gbh[cb][q], acc[q][m], 0, 0, 0);
                    }
            }
            __syncthreads();                   // B8: comb reads done

            // in-register cell
            float b0 = biasL[hc], b1 = biasL[128 + hc], b2 = biasL[256 + hc], b3 = biasL[384 + hc];
#pragma unroll
            for (int m = 0; m < 2; ++m)
#pragma unroll
                for (int r = 0; r < 4; ++r) {
                    int s = m * 4 + r;
                    int row = m * 16 + ((lane >> 4) << 2) + r;
                    float pi = acc[0][m][r] + b0;
                    float pf = acc[1][m][r] + b1;
                    float po = acc[2][m][r] + b2;
                    float pg = acc[3][m][r] + b3;
                    float ig = 1.f / (1.f + expf(-pi));
                    float fg = 1.f / (1.f + expf(-pf));
                    float og = 1.f / (1.f + expf(-po));
                    float gv = tanhf(pg);
                    float cv = fg * creg[s] + ig * gv;
                    creg[s] = cv;
                    float hv = og * tanhf(cv);
                    hbuf[row * 128 + (hc ^ ((row & 7) << 2))] = hv;
                    store2(combH, combM, row * 256 + ((64 + hc) ^ ((row & 7) << 3)), hv);
                }
        }
        __syncthreads();                       // B9: end of step
    }
}

// ---------------- fallback: round-7 single-WG kernel (verbatim, LDS-chunked social) ----------------
__global__ __launch_bounds__(512, 1) void slstm_main_fb(
    const float* __restrict__ obs_rel, const float* __restrict__ obs_abs,
    const float* __restrict__ We, const float* __restrict__ be,
    const float* __restrict__ bp,
    const float* __restrict__ bi, const float* __restrict__ bfv,
    const float* __restrict__ bo, const float* __restrict__ bg,
    const float* __restrict__ Wout, const float* __restrict__ bout,
    const unsigned short* __restrict__ W4H, const unsigned short* __restrict__ W4L,
    const unsigned short* __restrict__ WpH, const unsigned short* __restrict__ WpL,
    float* __restrict__ out) {

    __shared__ __align__(16) unsigned short combH[32 * 256];
    __shared__ __align__(16) unsigned short combM[32 * 256];
    __shared__ __align__(16) float hbuf[32 * 128];
    __shared__ __align__(16) float scratch[32 * 512];
    __shared__ float posb[64];
    __shared__ float pvbuf[64];
    __shared__ float red[256];
    __shared__ unsigned char binTab[1024];
    __shared__ unsigned char usedList[64];
    __shared__ unsigned char binSlotG[64];
    __shared__ unsigned short glist[1024];
    __shared__ unsigned long long gstartPacked[32];
    __shared__ int nUsedS;
    __shared__ unsigned usedMask[2];
    __shared__ unsigned jm[4];
    __shared__ float biasL[512], beL[64], bpL[64], WeL[128], WoutL[256], boutL[2];

    const int tid = threadIdx.x;
    const int lane = tid & 63;
    const int wv = tid >> 6;
    const int b = blockIdx.x;

    if (tid < 512) biasL[tid] = (tid < 128) ? bi[tid] : (tid < 256) ? bfv[tid - 128]
                              : (tid < 384) ? bo[tid - 256] : bg[tid - 384];
    if (tid < 64) { beL[tid] = be[tid]; bpL[tid] = bp[tid]; }
    if (tid < 128) WeL[tid] = We[tid];
    if (tid < 256) WoutL[tid] = Wout[tid];
    if (tid < 2) boutL[tid] = bout[tid];
    for (int x = tid; x < 32 * 256; x += 512) { combH[x] = 0; combM[x] = 0; }
    for (int x = tid; x < 32 * 128; x += 512) hbuf[x] = 0.f;
    float creg[8];
#pragma unroll
    for (int r = 0; r < 8; ++r) creg[r] = 0.f;
    __syncthreads();

    const float gnorm = (float)(2.0 / 7.0);
    const int gi = tid >> 4;
    const int gg = tid & 15;
    const int hc = wv * 16 + (lane & 15);

    for (int t = 0; t < NSTEPS; ++t) {
        if (t < OBS_T) {
            if (tid < 64) posb[tid] = obs_abs[t * 2048 + b * 64 + tid];
            {
                int e0 = gg * 4;
                float x0 = obs_rel[t * 2048 + b * 64 + gi * 2];
                float x1 = obs_rel[t * 2048 + b * 64 + gi * 2 + 1];
#pragma unroll
                for (int r = 0; r < 4; ++r) {
                    int e = e0 + r;
                    float v = x0 * WeL[e] + x1 * WeL[64 + e] + beL[e];
                    store2(combH, combM, gi * 256 + (e ^ ((gi & 7) << 3)), v);
                }
            }
        }
        if (tid < 2) usedMask[tid] = 0u;
        if (tid < 4) jm[tid] = 0u;
        __syncthreads();

        float sreg[4] = {0.f, 0.f, 0.f, 0.f};
        if (t > 0) {
#pragma unroll
            for (int pp = 0; pp < 2; ++pp) {
                int p = tid + pp * 512;
                int i = p >> 5, j = p & 31;
                float rx = (posb[j * 2]     - posb[i * 2])     / gnorm;
                float ry = (posb[j * 2 + 1] - posb[i * 2 + 1]) / gnorm;
                rx = fminf(fmaxf(rx, -4.f), 4.f);
                ry = fminf(fmaxf(ry, -4.f), 4.f);
                int gx = (int)(rx + 4.f);
                int gy = (int)(ry + 4.f);
                int valid = (gx < 8) && (gy < 8) && (i != j);
                int bin = gy * 8 + gx;
                binTab[p] = valid ? (unsigned char)bin : (unsigned char)255;
                if (valid) {
                    atomicOr(&usedMask[bin >> 5], 1u << (bin & 31));
                    atomicOr(&jm[((j < 16) ? 0 : 2) + (bin >> 5)], 1u << (bin & 31));
                }
            }
            __syncthreads();
            if (wv == 0) {
                bool used = (usedMask[lane >> 5] >> (lane & 31)) & 1u;
                unsigned long long bal = __ballot(used);
                int myIdx = __popcll(bal & ((1ull << lane) - 1ull));
                if (used) { usedList[myIdx] = (unsigned char)lane; }
                binSlotG[lane] = used ? (unsigned char)myIdx : (unsigned char)255;
                if (lane == 0) nUsedS = __popcll(bal);
            }
            __syncthreads();
            const int nUsed = nUsedS;
            const int nChunks = (nUsed + 7) >> 3;

            s8v Ahs[2][4], Ams[2][4];
#pragma unroll
            for (int m = 0; m < 2; ++m)
#pragma unroll
                for (int ks = 0; ks < 4; ++ks) {
                    int row = m * 16 + (lane & 15);
                    int k = ks * 32 + ((lane >> 4) << 3);
                    int ci = row * 256 + ((64 + k) ^ ((row & 7) << 3));
                    Ahs[m][ks] = *(const s8v*)&combH[ci];
                    Ams[m][ks] = *(const s8v*)&combM[ci];
                }

            if (tid < 32) {
                const int i = tid;
                unsigned rw[8];
#pragma unroll
                for (int w = 0; w < 8; ++w)
                    rw[w] = *(const unsigned*)&binTab[i * 32 + w * 4];
                unsigned long long cntp = 0;
#pragma unroll
                for (int j = 0; j < 32; ++j) {
                    unsigned bb = (rw[j >> 2] >> ((j & 3) * 8)) & 255u;
                    if (bb != 255u) cntp += 1ull << (5 * (binSlotG[bb] >> 3));
                }
                unsigned long long pre = 0; unsigned sum = 0;
#pragma unroll
                for (int c = 0; c < 8; ++c) {
                    pre |= (unsigned long long)sum << (5 * c);
                    sum += (unsigned)((cntp >> (5 * c)) & 31);
                }
                gstartPacked[i] = pre | ((unsigned long long)sum << 40);
                unsigned long long pos = pre;
#pragma unroll
                for (int j = 0; j < 32; ++j) {
                    unsigned bb = (rw[j >> 2] >> ((j & 3) * 8)) & 255u;
                    if (bb != 255u) {
                        int sg = binSlotG[bb];
                        int c = sg >> 3;
                        int p = (int)((pos >> (5 * c)) & 31);
                        glist[i * 32 + p] = (unsigned short)((sg << 5) | j);
                        pos += 1ull << (5 * c);
                    }
                }
            }

            unsigned long long spReg = 0;
            for (int c = 0; c < nChunks; ++c) {
                int idx = c * 8 + wv;
                if (idx < nUsed) {
                    int bin = usedList[idx];
                    const bool do0 = (jm[bin >> 5]       >> (bin & 31)) & 1;
                    const bool do1 = (jm[2 + (bin >> 5)] >> (bin & 31)) & 1;
#pragma unroll
                    for (int np = 0; np < 2; ++np) {
                        s8v bh0[4], bl0[4], bh1[4], bl1[4];
#pragma unroll
                        for (int ks = 0; ks < 4; ++ks) {
                            int foA = ((bin * 4 + np * 2)     * 4 + ks) * 64 + lane;
                            int foB = ((bin * 4 + np * 2 + 1) * 4 + ks) * 64 + lane;
                            bh0[ks] = ((const s8v*)WpH)[foA];
                            bl0[ks] = ((const s8v*)WpL)[foA];
                            bh1[ks] = ((const s8v*)WpH)[foB];
                            bl1[ks] = ((const s8v*)WpL)[foB];
                        }
                        if (do0) {
                            f32x4 a0 = {0.f, 0.f, 0.f, 0.f};
                            f32x4 a1 = {0.f, 0.f, 0.f, 0.f};
#pragma unroll
                            for (int ks = 0; ks < 4; ++ks) {
                                a0 = __builtin_amdgcn_mfma_f32_16x16x32_bf16(Ams[0][ks], bh0[ks], a0, 0, 0, 0);
                                a0 = __builtin_amdgcn_mfma_f32_16x16x32_bf16(Ahs[0][ks], bl0[ks], a0, 0, 0, 0);
                                a0 = __builtin_amdgcn_mfma_f32_16x16x32_bf16(Ahs[0][ks], bh0[ks], a0, 0, 0, 0);
                                a1 = __builtin_amdgcn_mfma_f32_16x16x32_bf16(Ams[0][ks], bh1[ks], a1, 0, 0, 0);
                                a1 = __builtin_amdgcn_mfma_f32_16x16x32_bf16(Ahs[0][ks], bl1[ks], a1, 0, 0, 0);
                                a1 = __builtin_amdgcn_mfma_f32_16x16x32_bf16(Ahs[0][ks], bh1[ks], a1, 0, 0, 0);
                            }
#pragma unroll
                            for (int nt = 0; nt < 2; ++nt) {
                                int e = (np * 2 + nt) * 16 + (lane & 15);
                                const f32x4 a = nt ? a1 : a0;
#pragma unroll
                                for (int r = 0; r < 4; ++r) {
                                    int j = ((lane >> 4) << 2) + r;
                                    scratch[j * 512 + wv * 64 + (e ^ (((j >> 2) & 3) << 4))] = a[r];
                                }
                            }
                        }
                        if (do1) {
                            f32x4 a0 = {0.f, 0.f, 0.f, 0.f};
                            f32x4 a1 = {0.f, 0.f, 0.f, 0.f};
#pragma unroll
                            for (int ks = 0; ks < 4; ++ks) {
                                a0 = __builtin_amdgcn_mfma_f32_16x16x32_bf16(Ams[1][ks], bh0[ks], a0, 0, 0, 0);
                                a0 = __builtin_amdgcn_mfma_f32_16x16x32_bf16(Ahs[1][ks], bl0[ks], a0, 0, 0, 0);
                                a0 = __builtin_amdgcn_mfma_f32_16x16x32_bf16(Ahs[1][ks], bh0[ks], a0, 0, 0, 0);
                                a1 = __builtin_amdgcn_mfma_f32_16x16x32_bf16(Ams[1][ks], bh1[ks], a1, 0, 0, 0);
                                a1 = __builtin_amdgcn_mfma_f32_16x16x32_bf16(Ahs[1][ks], bl1[ks], a1, 0, 0, 0);
                                a1 = __builtin_amdgcn_mfma_f32_16x16x32_bf16(Ahs[1][ks], bh1[ks], a1, 0, 0, 0);
                            }
#pragma unroll
                            for (int nt = 0; nt < 2; ++nt) {
                                int e = (np * 2 + nt) * 16 + (lane & 15);
                                const f32x4 a = nt ? a1 : a0;
#pragma unroll
                                for (int r = 0; r < 4; ++r) {
                                    int j = 16 + ((lane >> 4) << 2) + r;
                                    scratch[j * 512 + wv * 64 + (e ^ (((j >> 2) & 3) << 4))] = a[r];
                                }
                            }
                        }
                    }
                }
                __syncthreads();
                {
                    const int e0 = gg * 4;
                    if (c == 0) spReg = gstartPacked[gi];
                    int p0 = (int)((spReg >> (5 * c)) & 31);
                    int p1 = (int)((spReg >> (5 * c + 5)) & 31);
                    for (int p = p0; p < p1; ++p) {
                        unsigned en = glist[gi * 32 + p];
                        int slot = (en >> 5) & 7;
                        int j = en & 31;
                        const float4 y = *(const float4*)
                            &scratch[j * 512 + slot * 64 + (e0 ^ (((j >> 2) & 3) << 4))];
                        sreg[0] += y.x; sreg[1] += y.y; sreg[2] += y.z; sreg[3] += y.w;
                    }
                }
                __syncthreads();
            }
        }
        {
            int e0 = gg * 4;
#pragma unroll
            for (int r = 0; r < 4; ++r) {
                float v = fmaxf(sreg[r] + bpL[e0 + r], 0.f);
                store2(combH, combM, gi * 256 + ((192 + e0 + r) ^ ((gi & 7) << 3)), v);
            }
        }
        if (t >= OBS_T) {
            if (tid < 256) {
                int i = tid >> 3, d = (tid >> 2) & 1, pp = tid & 3;
                float acc = 0.f;
                int k0 = pp * 32;
                for (int k = k0; k < k0 + 32; ++k)
                    acc += hbuf[i * 128 + (k ^ ((i & 7) << 2))] * WoutL[k * 2 + d];
                red[tid] = acc;
            }
            __syncthreads();
            if (tid < 64) {
                int d = tid & 1;
                float pv = red[tid * 4] + red[tid * 4 + 1] + red[tid * 4 + 2] + red[tid * 4 + 3]
                         + boutL[d];
                out[(t - OBS_T) * 2048 + b * 64 + tid] = pv;
                posb[tid] += pv;
                pvbuf[tid] = pv;
            }
            __syncthreads();
            {
                int e0 = gg * 4;
                float x0 = pvbuf[gi * 2], x1 = pvbuf[gi * 2 + 1];
#pragma unroll
                for (int r = 0; r < 4; ++r) {
                    int e = e0 + r;
                    float v = x0 * WeL[e] + x1 * WeL[64 + e] + beL[e];
                    store2(combH, combM, gi * 256 + (e ^ ((gi & 7) << 3)), v);
                }
            }
        }
        __syncthreads();
        {
            f32x4 acc[4][2];
            f32x4 zero = {0.f, 0.f, 0.f, 0.f};
#pragma unroll
            for (int q = 0; q < 4; ++q) { acc[q][0] = zero; acc[q][1] = zero; }
            s8v gbh[2][4], gbl[2][4];
#pragma unroll
            for (int q = 0; q < 4; ++q) {
                int fo = ((wv * 4 + q) * 8 + 0) * 64 + lane;
                gbh[0][q] = ((const s8v*)W4H)[fo];
                gbl[0][q] = ((const s8v*)W4L)[fo];
            }
#pragma unroll
            for (int ks = 0; ks < 8; ++ks) {
                const int cb = ks & 1;
                if (ks < 7) {
#pragma unroll
                    for (int q = 0; q < 4; ++q) {
                        int fo = ((wv * 4 + q) * 8 + ks + 1) * 64 + lane;
                        gbh[cb ^ 1][q] = ((const s8v*)W4H)[fo];
                        gbl[cb ^ 1][q] = ((const s8v*)W4L)[fo];
                    }
                }
                s8v Ah[2], Am[2];
#pragma unroll
                for (int m = 0; m < 2; ++m) {
                    int row = m * 16 + (lane & 15);
                    int k = ks * 32 + ((lane >> 4) << 3);
                    int ci = row * 256 + (k ^ ((row & 7) << 3));
                    Ah[m] = *(const s8v*)&combH[ci];
                    Am[m] = *(const s8v*)&combM[ci];
                }
#pragma unroll
                for (int q = 0; q < 4; ++q)
#pragma unroll
                    for (int m = 0; m < 2; ++m) {
                        acc[q][m] = __builtin_amdgcn_mfma_f32_16x16x32_bf16(Am[m], gbh[cb][q], acc[q][m], 0, 0, 0);
                        acc[q][m] = __builtin_amdgcn_mfma_f32_16x16x32_bf16(Ah[m], gbl[cb][q], acc[q][m], 0, 0, 0);
                        acc[q][m] = __builtin_amdgcn_mfma_f32_16x16x32_bf16(Ah[m], gbh[cb][q], acc[q][m], 0, 0, 0);
                    }
            }
            __syncthreads();
            float b0 = biasL[hc], b1 = biasL[128 + hc], b2 = biasL[256 + hc], b3 = biasL[384 + hc];
#pragma unroll
            for (int m = 0; m < 2; ++m)
#pragma unroll
                for (int r = 0; r < 4; ++r) {
                    int s = m * 4 + r;
                    int row = m * 16 + ((lane >> 4) << 2) + r;
                    float pi = acc[0][m][r] + b0;
                    float pf = acc[1][m][r] + b1;
                    float po = acc[2][m][r] + b2;
                    float pg = acc[3][m][r] + b3;
                    float ig = 1.f / (1.f + expf(-pi));
                    float fg = 1.f / (1.f + expf(-pf));
                    float og = 1.f / (1.f + expf(-po));
                    float gv = tanhf(pg);
                    float cv = fg * creg[s] + ig * gv;
                    creg[s] = cv;
                    float hv = og * tanhf(cv);
                    hbuf[row * 128 + (hc ^ ((row & 7) << 2))] = hv;
                    store2(combH, combM, row * 256 + ((64 + hc) ^ ((row & 7) << 3)), hv);
                }
        }
        __syncthreads();
    }
}

extern "C" void kernel_launch(void* const* d_in, const int* in_sizes, int n_in,
                              void* d_out, int out_size, void* d_ws, size_t ws_size,
                              hipStream_t stream) {
    const float* obs_rel = (const float*)d_in[0];
    const float* obs_abs = (const float*)d_in[1];
    const float* We   = (const float*)d_in[3];
    const float* be   = (const float*)d_in[4];
    const float* Wp   = (const float*)d_in[5];
    const float* bp   = (const float*)d_in[6];
    const float* Wi   = (const float*)d_in[7];
    const float* bi   = (const float*)d_in[8];
    const float* Wf   = (const float*)d_in[9];
    const float* bf   = (const float*)d_in[10];
    const float* Wo   = (const float*)d_in[11];
    const float* bo   = (const float*)d_in[12];
    const float* Wg   = (const float*)d_in[13];
    const float* bg   = (const float*)d_in[14];
    const float* Wout = (const float*)d_in[15];
    const float* bout = (const float*)d_in[16];

    char* ws = (char*)d_ws;
    unsigned short* W4H = (unsigned short*)(ws + 0);
    unsigned short* W4L = (unsigned short*)(ws + 262144);
    unsigned short* WpH = (unsigned short*)(ws + 524288);
    unsigned short* WpL = (unsigned short*)(ws + 1572864);
    float* YG           = (float*)(ws + 2621440);     // 32 x 64 x 32 x 64 f32 = 16.7MB
    const size_t NEED   = 2621440 + 32ull * 524288;   // 19398656

    slstm_prep<<<2560, 256, 0, stream>>>(Wp, Wi, Wf, Wo, Wg, W4H, W4L, WpH, WpL);

    if (ws_size >= NEED) {
        slstm_mono<<<32, 512, 0, stream>>>(obs_rel, obs_abs, We, be, bp, bi, bf, bo, bg,
                                           Wout, bout, W4H, W4L, WpH, WpL, YG,
                                           (float*)d_out);
    } else {
        slstm_main_fb<<<32, 512, 0, stream>>>(obs_rel, obs_abs, We, be, bp, bi, bf, bo, bg,
                                              Wout, bout, W4H, W4L, WpH, WpL,
                                              (float*)d_out);
    }
}

// Round 15
// 581.792 us; speedup vs baseline: 2.1992x; 2.1992x over previous
//
#include <hip/hip_runtime.h>

typedef short s8v __attribute__((ext_vector_type(8)));
typedef float f32x4 __attribute__((ext_vector_type(4)));

#define OBS_T 8
#define NSTEPS 20

__device__ __forceinline__ unsigned short f2bf(float x) {
    unsigned u = __float_as_uint(x);
    u = (u + 0x7FFFu + ((u >> 16) & 1u)) >> 16;
    return (unsigned short)u;
}
__device__ __forceinline__ float bf2f(unsigned short h) {
    return __uint_as_float(((unsigned)h) << 16);
}
__device__ __forceinline__ void store2(unsigned short* H, unsigned short* M,
                                       int ci, float v) {
    unsigned short h = f2bf(v);
    H[ci] = h; M[ci] = f2bf(v - bf2f(h));
}

// ---------------- prep: pack x2-split bf16 weight fragments ----------------
__global__ void slstm_prep(const float* __restrict__ Wp,
                           const float* __restrict__ Wi, const float* __restrict__ Wf,
                           const float* __restrict__ Wo, const float* __restrict__ Wg,
                           unsigned short* __restrict__ W4H, unsigned short* __restrict__ W4L,
                           unsigned short* __restrict__ WpH, unsigned short* __restrict__ WpL) {
    int x = blockIdx.x * blockDim.x + threadIdx.x;
    const int NW4 = 32 * 8 * 64 * 8;      // 131072
    const int NWP = 64 * 4 * 4 * 64 * 8;  // 524288
    if (x < NW4) {
        int j = x & 7, lane = (x >> 3) & 63, ks = (x >> 9) & 7, nt2 = x >> 12;
        int q = nt2 & 3, wvb = nt2 >> 2;
        int col = wvb * 16 + (lane & 15);
        int k = ks * 32 + ((lane >> 4) << 3) + j;
        const float* W = (q == 0) ? Wi : (q == 1) ? Wf : (q == 2) ? Wo : Wg;
        float v = W[k * 128 + col];
        unsigned short h = f2bf(v);
        W4H[x] = h; W4L[x] = f2bf(v - bf2f(h));
    } else if (x < NW4 + NWP) {
        int y = x - NW4;
        int j = y & 7, lane = (y >> 3) & 63, ks = (y >> 9) & 3, nt = (y >> 11) & 3, bin = y >> 13;
        int e = nt * 16 + (lane & 15);
        int k = ks * 32 + ((lane >> 4) << 3) + j;
        float v = Wp[(bin * 128 + k) * 64 + e];
        unsigned short h = f2bf(v);
        WpH[y] = h; WpL[y] = f2bf(v - bf2f(h));
    }
}

struct SP {
    const float *obs_rel, *obs_abs, *We, *be, *bp, *bi, *bfv, *bo, *bg, *Wout, *bout;
    const unsigned short *W4H, *W4L, *WpH, *WpL;
    unsigned short *hBH, *hBM;
    float *hFG, *cG, *posG;
    unsigned char *ulG;       // [20][32][64]
    unsigned *jneedG;         // [20][32][64]
    int *nUG;                 // [20][32]
    unsigned short *glistG;   // [20][32][1024]
    unsigned long long *gstartG; // [20][32][32]
    float *YG;
    float *out;
};

// ---------------- bins precompute for t=1..8 (obs positions only) ----------------
__global__ __launch_bounds__(512, 2) void slstm_obsbins(SP p) {
    __shared__ float posb[64];
    __shared__ unsigned char binTabL[1024];
    __shared__ unsigned char binSlotL[64];
    __shared__ unsigned jneedS[64];

    const int seq = blockIdx.x & 31;
    const int tt = (blockIdx.x >> 5) + 1;      // step 1..8
    const int posIdx = (tt <= 7) ? tt : 7;     // bins(8) use obs[7]
    const int tid = threadIdx.x;
    const int lane = tid & 63;
    const int wv = tid >> 6;
    const float gnorm = (float)(2.0 / 7.0);
    const size_t mb = (size_t)(tt * 32 + seq);

    if (tid < 64) posb[tid] = p.obs_abs[posIdx * 2048 + seq * 64 + tid];
    if (tid < 64) jneedS[tid] = 0u;
    __syncthreads();
#pragma unroll
    for (int pp = 0; pp < 2; ++pp) {
        int pr = tid + pp * 512;
        int i = pr >> 5, j = pr & 31;
        float rx = (posb[j * 2]     - posb[i * 2])     / gnorm;
        float ry = (posb[j * 2 + 1] - posb[i * 2 + 1]) / gnorm;
        rx = fminf(fmaxf(rx, -4.f), 4.f);
        ry = fminf(fmaxf(ry, -4.f), 4.f);
        int gx = (int)(rx + 4.f);
        int gy = (int)(ry + 4.f);
        int valid = (gx < 8) && (gy < 8) && (i != j);
        int bin = gy * 8 + gx;
        binTabL[pr] = valid ? (unsigned char)bin : (unsigned char)255;
        if (valid) atomicOr(&jneedS[bin], 1u << j);
    }
    __syncthreads();
    if (wv == 0) {
        bool used = jneedS[lane] != 0u;
        unsigned long long bal = __ballot(used);
        int myIdx = __popcll(bal & ((1ull << lane) - 1ull));
        if (used) p.ulG[mb * 64 + myIdx] = (unsigned char)lane;
        binSlotL[lane] = used ? (unsigned char)myIdx : (unsigned char)255;
        if (lane == 0) p.nUG[mb] = (int)__popcll(bal);
    }
    if (tid < 64) p.jneedG[mb * 64 + tid] = jneedS[tid];
    __syncthreads();
    if (tid < 32) {
        const int i = tid;
        unsigned rw[8];
#pragma unroll
        for (int w = 0; w < 8; ++w)
            rw[w] = *(const unsigned*)&binTabL[i * 32 + w * 4];
        unsigned long long cntp = 0;
#pragma unroll
        for (int j = 0; j < 32; ++j) {
            unsigned bb = (rw[j >> 2] >> ((j & 3) * 8)) & 255u;
            if (bb != 255u) cntp += 1ull << (5 * (binSlotL[bb] >> 3));
        }
        unsigned long long pre = 0; unsigned sum = 0;
#pragma unroll
        for (int c = 0; c < 8; ++c) {
            pre |= (unsigned long long)sum << (5 * c);
            sum += (unsigned)((cntp >> (5 * c)) & 31);
        }
        p.gstartG[mb * 32 + i] = pre | ((unsigned long long)sum << 40);
        unsigned long long pos = pre;
#pragma unroll
        for (int j = 0; j < 32; ++j) {
            unsigned bb = (rw[j >> 2] >> ((j & 3) * 8)) & 255u;
            if (bb != 255u) {
                int sg = binSlotL[bb];
                int c = sg >> 3;
                int pidx = (int)((pos >> (5 * c)) & 31);
                p.glistG[mb * 1024 + i * 32 + pidx] = (unsigned short)((sg << 5) | j);
                pos += 1ull << (5 * c);
            }
        }
    }
}

// ---------------- kernel A: social Y-GEMM, 8 WGs per sequence (full chip) ----------------
// XCD-local: seq = blockIdx&31 -> all of a sequence's WGs share blockIdx%8.
__global__ __launch_bounds__(512, 2) void slstm_socialY(SP p, int t) {
    const int seq = blockIdx.x & 31;
    const int wrole = blockIdx.x >> 5;
    const int tid = threadIdx.x, lane = tid & 63, wv = tid >> 6;
    const int W = wrole * 8 + wv;          // 0..63 wave-units
    const int slotG = W >> 2;              // 0..15
    const int jhalf = (W >> 1) & 1;
    const int np = W & 1;                  // nt-pair
    const int arow = jhalf * 16 + (lane & 15);
    const int j4 = (lane >> 4) << 2;
    const unsigned short* hH = p.hBH + (size_t)seq * 4096;
    const unsigned short* hM = p.hBM + (size_t)seq * 4096;
    float* Yb = p.YG + (size_t)seq * 131072;
    const size_t mb = (size_t)(t * 32 + seq);
    const int nU = p.nUG[mb];

    s8v Ah[4], Am[4];
#pragma unroll
    for (int ks = 0; ks < 4; ++ks) {
        int o = arow * 128 + ks * 32 + ((lane >> 4) << 3);
        Ah[ks] = *(const s8v*)&hH[o];
        Am[ks] = *(const s8v*)&hM[o];
    }
    for (int slot = slotG; slot < nU; slot += 16) {
        int bin = p.ulG[mb * 64 + slot];
        unsigned halfmask = (p.jneedG[mb * 64 + bin] >> (16 * jhalf)) & 0xFFFFu;
        if (!halfmask) continue;
        s8v bh0[4], bl0[4], bh1[4], bl1[4];
#pragma unroll
        for (int ks = 0; ks < 4; ++ks) {
            int foA = ((bin * 4 + np * 2) * 4 + ks) * 64 + lane;
            int foB = ((bin * 4 + np * 2 + 1) * 4 + ks) * 64 + lane;
            bh0[ks] = ((const s8v*)p.WpH)[foA];
            bl0[ks] = ((const s8v*)p.WpL)[foA];
            bh1[ks] = ((const s8v*)p.WpH)[foB];
            bl1[ks] = ((const s8v*)p.WpL)[foB];
        }
        f32x4 a0 = {0.f, 0.f, 0.f, 0.f};
        f32x4 a1 = {0.f, 0.f, 0.f, 0.f};
#pragma unroll
        for (int ks = 0; ks < 4; ++ks) {
            a0 = __builtin_amdgcn_mfma_f32_16x16x32_bf16(Am[ks], bh0[ks], a0, 0, 0, 0);
            a0 = __builtin_amdgcn_mfma_f32_16x16x32_bf16(Ah[ks], bl0[ks], a0, 0, 0, 0);
            a0 = __builtin_amdgcn_mfma_f32_16x16x32_bf16(Ah[ks], bh0[ks], a0, 0, 0, 0);
            a1 = __builtin_amdgcn_mfma_f32_16x16x32_bf16(Am[ks], bh1[ks], a1, 0, 0, 0);
            a1 = __builtin_amdgcn_mfma_f32_16x16x32_bf16(Ah[ks], bl1[ks], a1, 0, 0, 0);
            a1 = __builtin_amdgcn_mfma_f32_16x16x32_bf16(Ah[ks], bh1[ks], a1, 0, 0, 0);
        }
#pragma unroll
        for (int nt = 0; nt < 2; ++nt) {
            int e = (np * 2 + nt) * 16 + (lane & 15);
            const f32x4 a = nt ? a1 : a0;
#pragma unroll
            for (int r = 0; r < 4; ++r) {
                if ((halfmask >> (j4 + r)) & 1u) {
                    int j = jhalf * 16 + j4 + r;
                    Yb[(slot * 32 + j) * 64 + e] = a[r];
                }
            }
        }
    }
}

// ---------------- kernel B: per-step master (gather + gates + cell + next-bins) ----------------
__global__ __launch_bounds__(512, 1) void slstm_step(SP p, int t) {
    __shared__ __align__(16) unsigned short combH[32 * 256];
    __shared__ __align__(16) unsigned short combM[32 * 256];
    __shared__ float posb[64];
    __shared__ float pvbuf[64];
    __shared__ float red[256];
    __shared__ unsigned char binTabL[1024];
    __shared__ unsigned char binSlotL[64];
    __shared__ unsigned jneedS[64];
    __shared__ float biasL[512], beL[64], bpL[64], WeL[128], WoutL[256], boutL[2];

    const int seq = blockIdx.x;
    const int tid = threadIdx.x;
    const int lane = tid & 63;
    const int wv = tid >> 6;
    const int gi = tid >> 4;
    const int gg = tid & 15;
    const int hc = wv * 16 + (lane & 15);
    const float gnorm = (float)(2.0 / 7.0);
    const size_t mb = (size_t)(t * 32 + seq);

    if (tid < 512) biasL[tid] = (tid < 128) ? p.bi[tid] : (tid < 256) ? p.bfv[tid - 128]
                              : (tid < 384) ? p.bo[tid - 256] : p.bg[tid - 384];
    if (tid < 64) { beL[tid] = p.be[tid]; bpL[tid] = p.bp[tid]; }
    if (tid < 128) WeL[tid] = p.We[tid];
    if (tid < 256) WoutL[tid] = p.Wout[tid];
    if (tid < 2) boutL[tid] = p.bout[tid];

    // h -> comb (cols 64..191), or zero at t==0
    if (t > 0) {
        for (int x = tid; x < 4096; x += 512) {
            int row = x >> 7, k = x & 127;
            int ci = row * 256 + ((64 + k) ^ ((row & 7) << 3));
            combH[ci] = p.hBH[seq * 4096 + x];
            combM[ci] = p.hBM[seq * 4096 + x];
        }
    } else {
        for (int x = tid; x < 4096; x += 512) {
            int row = x >> 7, k = x & 127;
            int ci = row * 256 + ((64 + k) ^ ((row & 7) << 3));
            combH[ci] = 0; combM[ci] = 0;
        }
    }
    __syncthreads();

    // ---------- gather s from Y ----------
    float sreg[4] = {0.f, 0.f, 0.f, 0.f};
    if (t > 0) {
        const int e0 = gg * 4;
        const unsigned long long sp = p.gstartG[mb * 32 + gi];
        const int cnt = (int)(sp >> 40);
        const unsigned short* gl = p.glistG + mb * 1024 + gi * 32;
        const float* Yb = p.YG + (size_t)seq * 131072;
        for (int p0 = 0; p0 < cnt; p0 += 4) {
            unsigned long long e4 = *(const unsigned long long*)&gl[p0];
            int n = cnt - p0;
            unsigned en0 = (unsigned)(e4 & 0xFFFF), en1 = (unsigned)((e4 >> 16) & 0xFFFF);
            unsigned en2 = (unsigned)((e4 >> 32) & 0xFFFF), en3 = (unsigned)((e4 >> 48) & 0xFFFF);
            float4 y0, y1, y2, y3;
            if (n > 0) y0 = *(const float4*)&Yb[(((en0 >> 5) * 32) + (en0 & 31)) * 64 + e0];
            if (n > 1) y1 = *(const float4*)&Yb[(((en1 >> 5) * 32) + (en1 & 31)) * 64 + e0];
            if (n > 2) y2 = *(const float4*)&Yb[(((en2 >> 5) * 32) + (en2 & 31)) * 64 + e0];
            if (n > 3) y3 = *(const float4*)&Yb[(((en3 >> 5) * 32) + (en3 & 31)) * 64 + e0];
            if (n > 0) { sreg[0] += y0.x; sreg[1] += y0.y; sreg[2] += y0.z; sreg[3] += y0.w; }
            if (n > 1) { sreg[0] += y1.x; sreg[1] += y1.y; sreg[2] += y1.z; sreg[3] += y1.w; }
            if (n > 2) { sreg[0] += y2.x; sreg[1] += y2.y; sreg[2] += y2.z; sreg[3] += y2.w; }
            if (n > 3) { sreg[0] += y3.x; sreg[1] += y3.y; sreg[2] += y3.z; sreg[3] += y3.w; }
        }
    }
    // finalize s = relu(pooled + bp) -> comb cols 192..255
    {
        int e0 = gg * 4;
#pragma unroll
        for (int r = 0; r < 4; ++r) {
            float v = fmaxf(sreg[r] + bpL[e0 + r], 0.f);
            store2(combH, combM, gi * 256 + ((192 + e0 + r) ^ ((gi & 7) << 3)), v);
        }
    }

    // ---------- E phase ----------
    if (t < OBS_T) {
        int e0 = gg * 4;
        float x0 = p.obs_rel[t * 2048 + seq * 64 + gi * 2];
        float x1 = p.obs_rel[t * 2048 + seq * 64 + gi * 2 + 1];
#pragma unroll
        for (int r = 0; r < 4; ++r) {
            int e = e0 + r;
            float v = x0 * WeL[e] + x1 * WeL[64 + e] + beL[e];
            store2(combH, combM, gi * 256 + (e ^ ((gi & 7) << 3)), v);
        }
    } else {
        if (tid < 64) posb[tid] = (t == OBS_T) ? p.obs_abs[7 * 2048 + seq * 64 + tid]
                                               : p.posG[seq * 64 + tid];
        if (tid < 256) {
            int i = tid >> 3, d = (tid >> 2) & 1, pp = tid & 3;
            float acc = 0.f;
            int k0 = pp * 32;
            for (int k = k0; k < k0 + 32; ++k)
                acc += p.hFG[seq * 4096 + i * 128 + k] * WoutL[k * 2 + d];
            red[tid] = acc;
        }
        __syncthreads();
        if (tid < 64) {
            int d = tid & 1;
            float pv = red[tid * 4] + red[tid * 4 + 1] + red[tid * 4 + 2] + red[tid * 4 + 3]
                     + boutL[d];
            p.out[(t - OBS_T) * 2048 + seq * 64 + tid] = pv;
            posb[tid] += pv;
            p.posG[seq * 64 + tid] = posb[tid];
            pvbuf[tid] = pv;
        }
        __syncthreads();
        {
            int e0 = gg * 4;
            float x0 = pvbuf[gi * 2], x1 = pvbuf[gi * 2 + 1];
#pragma unroll
            for (int r = 0; r < 4; ++r) {
                int e = e0 + r;
                float v = x0 * WeL[e] + x1 * WeL[64 + e] + beL[e];
                store2(combH, combM, gi * 256 + (e ^ ((gi & 7) << 3)), v);
            }
        }
    }
    __syncthreads();

    // ---------- gates (bf16x2 MFMA, ks-prefetched) ----------
    f32x4 acc[4][2];
    {
        f32x4 zero = {0.f, 0.f, 0.f, 0.f};
#pragma unroll
        for (int q = 0; q < 4; ++q) { acc[q][0] = zero; acc[q][1] = zero; }
        s8v gbh[2][4], gbl[2][4];
#pragma unroll
        for (int q = 0; q < 4; ++q) {
            int fo = ((wv * 4 + q) * 8 + 0) * 64 + lane;
            gbh[0][q] = ((const s8v*)p.W4H)[fo];
            gbl[0][q] = ((const s8v*)p.W4L)[fo];
        }
#pragma unroll
        for (int ks = 0; ks < 8; ++ks) {
            const int cb = ks & 1;
            if (ks < 7) {
#pragma unroll
                for (int q = 0; q < 4; ++q) {
                    int fo = ((wv * 4 + q) * 8 + ks + 1) * 64 + lane;
                    gbh[cb ^ 1][q] = ((const s8v*)p.W4H)[fo];
                    gbl[cb ^ 1][q] = ((const s8v*)p.W4L)[fo];
                }
            }
            s8v Ah[2], Am[2];
#pragma unroll
            for (int m = 0; m < 2; ++m) {
                int row = m * 16 + (lane & 15);
                int k = ks * 32 + ((lane >> 4) << 3);
                int ci = row * 256 + (k ^ ((row & 7) << 3));
                Ah[m] = *(const s8v*)&combH[ci];
                Am[m] = *(const s8v*)&combM[ci];
            }
#pragma unroll
            for (int q = 0; q < 4; ++q)
#pragma unroll
                for (int m = 0; m < 2; ++m) {
                    acc[q][m] = __builtin_amdgcn_mfma_f32_16x16x32_bf16(Am[m], gbh[cb][q], acc[q][m], 0, 0, 0);
                    acc[q][m] = __builtin_amdgcn_mfma_f32_16x16x32_bf16(Ah[m], gbl[cb][q], acc[q][m], 0, 0, 0);
                    acc[q][m] = __builtin_amdgcn_mfma_f32_16x16x32_bf16(Ah[m], gbh[cb][q], acc[q][m], 0, 0, 0);
                }
        }
    }

    // ---------- cell (global state round-trip) ----------
    {
        float b0 = biasL[hc], b1 = biasL[128 + hc], b2 = biasL[256 + hc], b3 = biasL[384 + hc];
#pragma unroll
        for (int m = 0; m < 2; ++m)
#pragma unroll
            for (int r = 0; r < 4; ++r) {
                int row = m * 16 + ((lane >> 4) << 2) + r;
                int gidx = seq * 4096 + row * 128 + hc;
                float cprev = (t > 0) ? p.cG[gidx] : 0.f;
                float pi = acc[0][m][r] + b0;
                float pf = acc[1][m][r] + b1;
                float po = acc[2][m][r] + b2;
                float pg = acc[3][m][r] + b3;
                float ig = 1.f / (1.f + expf(-pi));
                float fg = 1.f / (1.f + expf(-pf));
                float og = 1.f / (1.f + expf(-po));
                float gv = tanhf(pg);
                float cv = fg * cprev + ig * gv;
                p.cG[gidx] = cv;
                float hv = og * tanhf(cv);
                p.hFG[gidx] = hv;
                unsigned short hh = f2bf(hv);
                float r1 = hv - bf2f(hh);
                p.hBH[gidx] = hh;
                p.hBM[gidx] = f2bf(r1);
            }
    }

    // ---------- tail: bins/glist for step t+1 (only pred-phase steps; obs ones precomputed) ----------
    if (t >= OBS_T && t < NSTEPS - 1) {
        const size_t nb = (size_t)((t + 1) * 32 + seq);
        // posb holds pos(t+1) from E_pred update above
        if (tid < 64) jneedS[tid] = 0u;
        __syncthreads();
#pragma unroll
        for (int pp = 0; pp < 2; ++pp) {
            int pr = tid + pp * 512;
            int i = pr >> 5, j = pr & 31;
            float rx = (posb[j * 2]     - posb[i * 2])     / gnorm;
            float ry = (posb[j * 2 + 1] - posb[i * 2 + 1]) / gnorm;
            rx = fminf(fmaxf(rx, -4.f), 4.f);
            ry = fminf(fmaxf(ry, -4.f), 4.f);
            int gx = (int)(rx + 4.f);
            int gy = (int)(ry + 4.f);
            int valid = (gx < 8) && (gy < 8) && (i != j);
            int bin = gy * 8 + gx;
            binTabL[pr] = valid ? (unsigned char)bin : (unsigned char)255;
            if (valid) atomicOr(&jneedS[bin], 1u << j);
        }
        __syncthreads();
        if (wv == 0) {
            bool used = jneedS[lane] != 0u;
            unsigned long long bal = __ballot(used);
            int myIdx = __popcll(bal & ((1ull << lane) - 1ull));
            if (used) p.ulG[nb * 64 + myIdx] = (unsigned char)lane;
            binSlotL[lane] = used ? (unsigned char)myIdx : (unsigned char)255;
            if (lane == 0) p.nUG[nb] = (int)__popcll(bal);
        }
        if (tid < 64) p.jneedG[nb * 64 + tid] = jneedS[tid];
        __syncthreads();
        if (tid < 32) {
            const int i = tid;
            unsigned rw[8];
#pragma unroll
            for (int w = 0; w < 8; ++w)
                rw[w] = *(const unsigned*)&binTabL[i * 32 + w * 4];
            unsigned long long cntp = 0;
#pragma unroll
            for (int j = 0; j < 32; ++j) {
                unsigned bb = (rw[j >> 2] >> ((j & 3) * 8)) & 255u;
                if (bb != 255u) cntp += 1ull << (5 * (binSlotL[bb] >> 3));
            }
            unsigned long long pre = 0; unsigned sum = 0;
#pragma unroll
            for (int c = 0; c < 8; ++c) {
                pre |= (unsigned long long)sum << (5 * c);
                sum += (unsigned)((cntp >> (5 * c)) & 31);
            }
            p.gstartG[nb * 32 + i] = pre | ((unsigned long long)sum << 40);
            unsigned long long pos = pre;
#pragma unroll
            for (int j = 0; j < 32; ++j) {
                unsigned bb = (rw[j >> 2] >> ((j & 3) * 8)) & 255u;
                if (bb != 255u) {
                    int sg = binSlotL[bb];
                    int c = sg >> 3;
                    int pidx = (int)((pos >> (5 * c)) & 31);
                    p.glistG[nb * 1024 + i * 32 + pidx] = (unsigned short)((sg << 5) | j);
                    pos += 1ull << (5 * c);
                }
            }
        }
    }
}

// ---------------- fallback: round-7 single-WG kernel (verbatim) ----------------
__global__ __launch_bounds__(512, 1) void slstm_main_fb(
    const float* __restrict__ obs_rel, const float* __restrict__ obs_abs,
    const float* __restrict__ We, const float* __restrict__ be,
    const float* __restrict__ bp,
    const float* __restrict__ bi, const float* __restrict__ bfv,
    const float* __restrict__ bo, const float* __restrict__ bg,
    const float* __restrict__ Wout, const float* __restrict__ bout,
    const unsigned short* __restrict__ W4H, const unsigned short* __restrict__ W4L,
    const unsigned short* __restrict__ WpH, const unsigned short* __restrict__ WpL,
    float* __restrict__ out) {

    __shared__ __align__(16) unsigned short combH[32 * 256];
    __shared__ __align__(16) unsigned short combM[32 * 256];
    __shared__ __align__(16) float hbuf[32 * 128];
    __shared__ __align__(16) float scratch[32 * 512];
    __shared__ float posb[64];
    __shared__ float pvbuf[64];
    __shared__ float red[256];
    __shared__ unsigned char binTab[1024];
    __shared__ unsigned char usedList[64];
    __shared__ unsigned char binSlotG[64];
    __shared__ unsigned short glist[1024];
    __shared__ unsigned long long gstartPacked[32];
    __shared__ int nUsedS;
    __shared__ unsigned usedMask[2];
    __shared__ unsigned jm[4];
    __shared__ float biasL[512], beL[64], bpL[64], WeL[128], WoutL[256], boutL[2];

    const int tid = threadIdx.x;
    const int lane = tid & 63;
    const int wv = tid >> 6;
    const int b = blockIdx.x;

    if (tid < 512) biasL[tid] = (tid < 128) ? bi[tid] : (tid < 256) ? bfv[tid - 128]
                              : (tid < 384) ? bo[tid - 256] : bg[tid - 384];
    if (tid < 64) { beL[tid] = be[tid]; bpL[tid] = bp[tid]; }
    if (tid < 128) WeL[tid] = We[tid];
    if (tid < 256) WoutL[tid] = Wout[tid];
    if (tid < 2) boutL[tid] = bout[tid];
    for (int x = tid; x < 32 * 256; x += 512) { combH[x] = 0; combM[x] = 0; }
    for (int x = tid; x < 32 * 128; x += 512) hbuf[x] = 0.f;
    float creg[8];
#pragma unroll
    for (int r = 0; r < 8; ++r) creg[r] = 0.f;
    __syncthreads();

    const float gnorm = (float)(2.0 / 7.0);
    const int gi = tid >> 4;
    const int gg = tid & 15;
    const int hc = wv * 16 + (lane & 15);

    for (int t = 0; t < NSTEPS; ++t) {
        if (t < OBS_T) {
            if (tid < 64) posb[tid] = obs_abs[t * 2048 + b * 64 + tid];
            {
                int e0 = gg * 4;
                float x0 = obs_rel[t * 2048 + b * 64 + gi * 2];
                float x1 = obs_rel[t * 2048 + b * 64 + gi * 2 + 1];
#pragma unroll
                for (int r = 0; r < 4; ++r) {
                    int e = e0 + r;
                    float v = x0 * WeL[e] + x1 * WeL[64 + e] + beL[e];
                    store2(combH, combM, gi * 256 + (e ^ ((gi & 7) << 3)), v);
                }
            }
        }
        if (tid < 2) usedMask[tid] = 0u;
        if (tid < 4) jm[tid] = 0u;
        __syncthreads();

        float sreg[4] = {0.f, 0.f, 0.f, 0.f};
        if (t > 0) {
#pragma unroll
            for (int pp = 0; pp < 2; ++pp) {
                int p = tid + pp * 512;
                int i = p >> 5, j = p & 31;
                float rx = (posb[j * 2]     - posb[i * 2])     / gnorm;
                float ry = (posb[j * 2 + 1] - posb[i * 2 + 1]) / gnorm;
                rx = fminf(fmaxf(rx, -4.f), 4.f);
                ry = fminf(fmaxf(ry, -4.f), 4.f);
                int gx = (int)(rx + 4.f);
                int gy = (int)(ry + 4.f);
                int valid = (gx < 8) && (gy < 8) && (i != j);
                int bin = gy * 8 + gx;
                binTab[p] = valid ? (unsigned char)bin : (unsigned char)255;
                if (valid) {
                    atomicOr(&usedMask[bin >> 5], 1u << (bin & 31));
                    atomicOr(&jm[((j < 16) ? 0 : 2) + (bin >> 5)], 1u << (bin & 31));
                }
            }
            __syncthreads();
            if (wv == 0) {
                bool used = (usedMask[lane >> 5] >> (lane & 31)) & 1u;
                unsigned long long bal = __ballot(used);
                int myIdx = __popcll(bal & ((1ull << lane) - 1ull));
                if (used) { usedList[myIdx] = (unsigned char)lane; }
                binSlotG[lane] = used ? (unsigned char)myIdx : (unsigned char)255;
                if (lane == 0) nUsedS = __popcll(bal);
            }
            __syncthreads();
            const int nUsed = nUsedS;
            const int nChunks = (nUsed + 7) >> 3;

            s8v Ahs[2][4], Ams[2][4];
#pragma unroll
            for (int m = 0; m < 2; ++m)
#pragma unroll
                for (int ks = 0; ks < 4; ++ks) {
                    int row = m * 16 + (lane & 15);
                    int k = ks * 32 + ((lane >> 4) << 3);
                    int ci = row * 256 + ((64 + k) ^ ((row & 7) << 3));
                    Ahs[m][ks] = *(const s8v*)&combH[ci];
                    Ams[m][ks] = *(const s8v*)&combM[ci];
                }

            if (tid < 32) {
                const int i = tid;
                unsigned rw[8];
#pragma unroll
                for (int w = 0; w < 8; ++w)
                    rw[w] = *(const unsigned*)&binTab[i * 32 + w * 4];
                unsigned long long cntp = 0;
#pragma unroll
                for (int j = 0; j < 32; ++j) {
                    unsigned bb = (rw[j >> 2] >> ((j & 3) * 8)) & 255u;
                    if (bb != 255u) cntp += 1ull << (5 * (binSlotG[bb] >> 3));
                }
                unsigned long long pre = 0; unsigned sum = 0;
#pragma unroll
                for (int c = 0; c < 8; ++c) {
                    pre |= (unsigned long long)sum << (5 * c);
                    sum += (unsigned)((cntp >> (5 * c)) & 31);
                }
                gstartPacked[i] = pre | ((unsigned long long)sum << 40);
                unsigned long long pos = pre;
#pragma unroll
                for (int j = 0; j < 32; ++j) {
                    unsigned bb = (rw[j >> 2] >> ((j & 3) * 8)) & 255u;
                    if (bb != 255u) {
                        int sg = binSlotG[bb];
                        int c = sg >> 3;
                        int p = (int)((pos >> (5 * c)) & 31);
                        glist[i * 32 + p] = (unsigned short)((sg << 5) | j);
                        pos += 1ull << (5 * c);
                    }
                }
            }

            unsigned long long spReg = 0;
            for (int c = 0; c < nChunks; ++c) {
                int idx = c * 8 + wv;
                if (idx < nUsed) {
                    int bin = usedList[idx];
                    const bool do0 = (jm[bin >> 5]       >> (bin & 31)) & 1;
                    const bool do1 = (jm[2 + (bin >> 5)] >> (bin & 31)) & 1;
#pragma unroll
                    for (int np = 0; np < 2; ++np) {
                        s8v bh0[4], bl0[4], bh1[4], bl1[4];
#pragma unroll
                        for (int ks = 0; ks < 4; ++ks) {
                            int foA = ((bin * 4 + np * 2)     * 4 + ks) * 64 + lane;
                            int foB = ((bin * 4 + np * 2 + 1) * 4 + ks) * 64 + lane;
                            bh0[ks] = ((const s8v*)WpH)[foA];
                            bl0[ks] = ((const s8v*)WpL)[foA];
                            bh1[ks] = ((const s8v*)WpH)[foB];
                            bl1[ks] = ((const s8v*)WpL)[foB];
                        }
                        if (do0) {
                            f32x4 a0 = {0.f, 0.f, 0.f, 0.f};
                            f32x4 a1 = {0.f, 0.f, 0.f, 0.f};
#pragma unroll
                            for (int ks = 0; ks < 4; ++ks) {
                                a0 = __builtin_amdgcn_mfma_f32_16x16x32_bf16(Ams[0][ks], bh0[ks], a0, 0, 0, 0);
                                a0 = __builtin_amdgcn_mfma_f32_16x16x32_bf16(Ahs[0][ks], bl0[ks], a0, 0, 0, 0);
                                a0 = __builtin_amdgcn_mfma_f32_16x16x32_bf16(Ahs[0][ks], bh0[ks], a0, 0, 0, 0);
                                a1 = __builtin_amdgcn_mfma_f32_16x16x32_bf16(Ams[0][ks], bh1[ks], a1, 0, 0, 0);
                                a1 = __builtin_amdgcn_mfma_f32_16x16x32_bf16(Ahs[0][ks], bl1[ks], a1, 0, 0, 0);
                                a1 = __builtin_amdgcn_mfma_f32_16x16x32_bf16(Ahs[0][ks], bh1[ks], a1, 0, 0, 0);
                            }
#pragma unroll
                            for (int nt = 0; nt < 2; ++nt) {
                                int e = (np * 2 + nt) * 16 + (lane & 15);
                                const f32x4 a = nt ? a1 : a0;
#pragma unroll
                                for (int r = 0; r < 4; ++r) {
                                    int j = ((lane >> 4) << 2) + r;
                                    scratch[j * 512 + wv * 64 + (e ^ (((j >> 2) & 3) << 4))] = a[r];
                                }
                            }
                        }
                        if (do1) {
                            f32x4 a0 = {0.f, 0.f, 0.f, 0.f};
                            f32x4 a1 = {0.f, 0.f, 0.f, 0.f};
#pragma unroll
                            for (int ks = 0; ks < 4; ++ks) {
                                a0 = __builtin_amdgcn_mfma_f32_16x16x32_bf16(Ams[1][ks], bh0[ks], a0, 0, 0, 0);
                                a0 = __builtin_amdgcn_mfma_f32_16x16x32_bf16(Ahs[1][ks], bl0[ks], a0, 0, 0, 0);
                                a0 = __builtin_amdgcn_mfma_f32_16x16x32_bf16(Ahs[1][ks], bh0[ks], a0, 0, 0, 0);
                                a1 = __builtin_amdgcn_mfma_f32_16x16x32_bf16(Ams[1][ks], bh1[ks], a1, 0, 0, 0);
                                a1 = __builtin_amdgcn_mfma_f32_16x16x32_bf16(Ahs[1][ks], bl1[ks], a1, 0, 0, 0);
                                a1 = __builtin_amdgcn_mfma_f32_16x16x32_bf16(Ahs[1][ks], bh1[ks], a1, 0, 0, 0);
                            }
#pragma unroll
                            for (int nt = 0; nt < 2; ++nt) {
                                int e = (np * 2 + nt) * 16 + (lane & 15);
                                const f32x4 a = nt ? a1 : a0;
#pragma unroll
                                for (int r = 0; r < 4; ++r) {
                                    int j = 16 + ((lane >> 4) << 2) + r;
                                    scratch[j * 512 + wv * 64 + (e ^ (((j >> 2) & 3) << 4))] = a[r];
                                }
                            }
                        }
                    }
                }
                __syncthreads();
                {
                    const int e0 = gg * 4;
                    if (c == 0) spReg = gstartPacked[gi];
                    int p0 = (int)((spReg >> (5 * c)) & 31);
                    int p1 = (int)((spReg >> (5 * c + 5)) & 31);
                    for (int p = p0; p < p1; ++p) {
                        unsigned en = glist[gi * 32 + p];
                        int slot = (en >> 5) & 7;
                        int j = en & 31;
                        const float4 y = *(const float4*)
                            &scratch[j * 512 + slot * 64 + (e0 ^ (((j >> 2) & 3) << 4))];
                        sreg[0] += y.x; sreg[1] += y.y; sreg[2] += y.z; sreg[3] += y.w;
                    }
                }
                __syncthreads();
            }
        }
        {
            int e0 = gg * 4;
#pragma unroll
            for (int r = 0; r < 4; ++r) {
                float v = fmaxf(sreg[r] + bpL[e0 + r], 0.f);
                store2(combH, combM, gi * 256 + ((192 + e0 + r) ^ ((gi & 7) << 3)), v);
            }
        }
        if (t >= OBS_T) {
            if (tid < 256) {
                int i = tid >> 3, d = (tid >> 2) & 1, pp = tid & 3;
                float acc = 0.f;
                int k0 = pp * 32;
                for (int k = k0; k < k0 + 32; ++k)
                    acc += hbuf[i * 128 + (k ^ ((i & 7) << 2))] * WoutL[k * 2 + d];
                red[tid] = acc;
            }
            __syncthreads();
            if (tid < 64) {
                int d = tid & 1;
                float pv = red[tid * 4] + red[tid * 4 + 1] + red[tid * 4 + 2] + red[tid * 4 + 3]
                         + boutL[d];
                out[(t - OBS_T) * 2048 + b * 64 + tid] = pv;
                posb[tid] += pv;
                pvbuf[tid] = pv;
            }
            __syncthreads();
            {
                int e0 = gg * 4;
                float x0 = pvbuf[gi * 2], x1 = pvbuf[gi * 2 + 1];
#pragma unroll
                for (int r = 0; r < 4; ++r) {
                    int e = e0 + r;
                    float v = x0 * WeL[e] + x1 * WeL[64 + e] + beL[e];
                    store2(combH, combM, gi * 256 + (e ^ ((gi & 7) << 3)), v);
                }
            }
        }
        __syncthreads();
        {
            f32x4 acc[4][2];
            f32x4 zero = {0.f, 0.f, 0.f, 0.f};
#pragma unroll
            for (int q = 0; q < 4; ++q) { acc[q][0] = zero; acc[q][1] = zero; }
            s8v gbh[2][4], gbl[2][4];
#pragma unroll
            for (int q = 0; q < 4; ++q) {
                int fo = ((wv * 4 + q) * 8 + 0) * 64 + lane;
                gbh[0][q] = ((const s8v*)W4H)[fo];
                gbl[0][q] = ((const s8v*)W4L)[fo];
            }
#pragma unroll
            for (int ks = 0; ks < 8; ++ks) {
                const int cb = ks & 1;
                if (ks < 7) {
#pragma unroll
                    for (int q = 0; q < 4; ++q) {
                        int fo = ((wv * 4 + q) * 8 + ks + 1) * 64 + lane;
                        gbh[cb ^ 1][q] = ((const s8v*)W4H)[fo];
                        gbl[cb ^ 1][q] = ((const s8v*)W4L)[fo];
                    }
                }
                s8v Ah[2], Am[2];
#pragma unroll
                for (int m = 0; m < 2; ++m) {
                    int row = m * 16 + (lane & 15);
                    int k = ks * 32 + ((lane >> 4) << 3);
                    int ci = row * 256 + (k ^ ((row & 7) << 3));
                    Ah[m] = *(const s8v*)&combH[ci];
                    Am[m] = *(const s8v*)&combM[ci];
                }
#pragma unroll
                for (int q = 0; q < 4; ++q)
#pragma unroll
                    for (int m = 0; m < 2; ++m) {
                        acc[q][m] = __builtin_amdgcn_mfma_f32_16x16x32_bf16(Am[m], gbh[cb][q], acc[q][m], 0, 0, 0);
                        acc[q][m] = __builtin_amdgcn_mfma_f32_16x16x32_bf16(Ah[m], gbl[cb][q], acc[q][m], 0, 0, 0);
                        acc[q][m] = __builtin_amdgcn_mfma_f32_16x16x32_bf16(Ah[m], gbh[cb][q], acc[q][m], 0, 0, 0);
                    }
            }
            __syncthreads();
            float b0 = biasL[hc], b1 = biasL[128 + hc], b2 = biasL[256 + hc], b3 = biasL[384 + hc];
#pragma unroll
            for (int m = 0; m < 2; ++m)
#pragma unroll
                for (int r = 0; r < 4; ++r) {
                    int s = m * 4 + r;
                    int row = m * 16 + ((lane >> 4) << 2) + r;
                    float pi = acc[0][m][r] + b0;
                    float pf = acc[1][m][r] + b1;
                    float po = acc[2][m][r] + b2;
                    float pg = acc[3][m][r] + b3;
                    float ig = 1.f / (1.f + expf(-pi));
                    float fg = 1.f / (1.f + expf(-pf));
                    float og = 1.f / (1.f + expf(-po));
                    float gv = tanhf(pg);
                    float cv = fg * creg[s] + ig * gv;
                    creg[s] = cv;
                    float hv = og * tanhf(cv);
                    hbuf[row * 128 + (hc ^ ((row & 7) << 2))] = hv;
                    store2(combH, combM, row * 256 + ((64 + hc) ^ ((row & 7) << 3)), hv);
                }
        }
        __syncthreads();
    }
}

extern "C" void kernel_launch(void* const* d_in, const int* in_sizes, int n_in,
                              void* d_out, int out_size, void* d_ws, size_t ws_size,
                              hipStream_t stream) {
    const float* obs_rel = (const float*)d_in[0];
    const float* obs_abs = (const float*)d_in[1];
    const float* We   = (const float*)d_in[3];
    const float* be   = (const float*)d_in[4];
    const float* Wp   = (const float*)d_in[5];
    const float* bp   = (const float*)d_in[6];
    const float* Wi   = (const float*)d_in[7];
    const float* bi   = (const float*)d_in[8];
    const float* Wf   = (const float*)d_in[9];
    const float* bf   = (const float*)d_in[10];
    const float* Wo   = (const float*)d_in[11];
    const float* bo   = (const float*)d_in[12];
    const float* Wg   = (const float*)d_in[13];
    const float* bg   = (const float*)d_in[14];
    const float* Wout = (const float*)d_in[15];
    const float* bout = (const float*)d_in[16];

    char* ws = (char*)d_ws;
    unsigned short* W4H = (unsigned short*)(ws + 0);
    unsigned short* W4L = (unsigned short*)(ws + 262144);
    unsigned short* WpH = (unsigned short*)(ws + 524288);
    unsigned short* WpL = (unsigned short*)(ws + 1572864);
    unsigned short* hBH = (unsigned short*)(ws + 2621440);
    unsigned short* hBM = (unsigned short*)(ws + 2883584);
    float* hFG          = (float*)(ws + 3145728);
    float* cG           = (float*)(ws + 3670016);
    float* posG         = (float*)(ws + 4194304);
    unsigned char* ulG  = (unsigned char*)(ws + 4202496);      // [20][32][64]  -> 40960
    unsigned* jneedG    = (unsigned*)(ws + 4243456);           // [20][32][64]u32 -> 163840
    int* nUG            = (int*)(ws + 4407296);                // [20][32] -> 2560
    unsigned long long* gstartG = (unsigned long long*)(ws + 4409856); // [20][32][32] -> 163840
    unsigned short* glistG = (unsigned short*)(ws + 4573696);  // [20][32][1024] -> 1310720
    float* YG           = (float*)(ws + 5884416);              // 32x131072 f32 = 16777216
    const size_t NEED   = 22661632;

    slstm_prep<<<2560, 256, 0, stream>>>(Wp, Wi, Wf, Wo, Wg, W4H, W4L, WpH, WpL);

    if (ws_size >= NEED) {
        SP p;
        p.obs_rel = obs_rel; p.obs_abs = obs_abs; p.We = We; p.be = be; p.bp = bp;
        p.bi = bi; p.bfv = bf; p.bo = bo; p.bg = bg; p.Wout = Wout; p.bout = bout;
        p.W4H = W4H; p.W4L = W4L; p.WpH = WpH; p.WpL = WpL;
        p.hBH = hBH; p.hBM = hBM; p.hFG = hFG; p.cG = cG; p.posG = posG;
        p.ulG = ulG; p.jneedG = jneedG; p.nUG = nUG;
        p.glistG = glistG; p.gstartG = gstartG; p.YG = YG; p.out = (float*)d_out;

        slstm_obsbins<<<256, 512, 0, stream>>>(p);
        slstm_step<<<32, 512, 0, stream>>>(p, 0);
        for (int t = 1; t < NSTEPS; ++t) {
            slstm_socialY<<<256, 512, 0, stream>>>(p, t);
            slstm_step<<<32, 512, 0, stream>>>(p, t);
        }
    } else {
        slstm_main_fb<<<32, 512, 0, stream>>>(obs_rel, obs_abs, We, be, bp, bi, bf, bo, bg,
                                              Wout, bout, W4H, W4L, WpH, WpL,
                                              (float*)d_out);
    }
}

// Round 16
// 576.561 us; speedup vs baseline: 2.2191x; 1.0091x over previous
//
#include <hip/hip_runtime.h>

typedef short s8v __attribute__((ext_vector_type(8)));
typedef float f32x4 __attribute__((ext_vector_type(4)));

#define OBS_T 8
#define NSTEPS 20

__device__ __forceinline__ unsigned short f2bf(float x) {
    unsigned u = __float_as_uint(x);
    u = (u + 0x7FFFu + ((u >> 16) & 1u)) >> 16;
    return (unsigned short)u;
}
__device__ __forceinline__ float bf2f(unsigned short h) {
    return __uint_as_float(((unsigned)h) << 16);
}
__device__ __forceinline__ void store2(unsigned short* H, unsigned short* M,
                                       int ci, float v) {
    unsigned short h = f2bf(v);
    H[ci] = h; M[ci] = f2bf(v - bf2f(h));
}

struct SP {
    const float *obs_rel, *obs_abs, *We, *be, *bp, *bi, *bfv, *bo, *bg, *Wout, *bout;
    const unsigned short *W4H, *W4L, *WpH, *WpL;
    unsigned short *hBH, *hBM;
    float *hFG, *cG, *posG;
    unsigned char *ulG;       // [20][32][64]
    unsigned *jneedG;         // [20][32][64]
    int *nUG;                 // [20][32]
    unsigned short *glistG;   // [20][32][1024]
    unsigned long long *gstartG; // [20][32][32]
    float *YG;
    float *out;
};

// ---------------- fused pre-kernel: weight packing (blocks 256..575) + obs bins (blocks 0..255) ----------------
__global__ __launch_bounds__(512, 2) void slstm_pre(SP p,
    const float* __restrict__ Wp,
    const float* __restrict__ Wi, const float* __restrict__ Wf,
    const float* __restrict__ Wo, const float* __restrict__ Wg,
    unsigned short* __restrict__ W4H, unsigned short* __restrict__ W4L,
    unsigned short* __restrict__ WpH, unsigned short* __restrict__ WpL) {
    __shared__ float posb[64];
    __shared__ unsigned char binTabL[1024];
    __shared__ unsigned char binSlotL[64];
    __shared__ unsigned jneedS[64];

    const int tid = threadIdx.x;

    if (blockIdx.x >= 256) {
        // -------- weight packing: 4 elements per thread --------
        const int NW4 = 32 * 8 * 64 * 8;      // 131072
        const int NWP = 64 * 4 * 4 * 64 * 8;  // 524288
        int base = (((int)blockIdx.x - 256) * 512 + tid) * 4;
#pragma unroll
        for (int u = 0; u < 4; ++u) {
            int x = base + u;
            if (x < NW4) {
                int j = x & 7, lane = (x >> 3) & 63, ks = (x >> 9) & 7, nt2 = x >> 12;
                int q = nt2 & 3, wvb = nt2 >> 2;
                int col = wvb * 16 + (lane & 15);
                int k = ks * 32 + ((lane >> 4) << 3) + j;
                const float* W = (q == 0) ? Wi : (q == 1) ? Wf : (q == 2) ? Wo : Wg;
                float v = W[k * 128 + col];
                unsigned short h = f2bf(v);
                W4H[x] = h; W4L[x] = f2bf(v - bf2f(h));
            } else if (x < NW4 + NWP) {
                int y = x - NW4;
                int j = y & 7, lane = (y >> 3) & 63, ks = (y >> 9) & 3, nt = (y >> 11) & 3, bin = y >> 13;
                int e = nt * 16 + (lane & 15);
                int k = ks * 32 + ((lane >> 4) << 3) + j;
                float v = Wp[(bin * 128 + k) * 64 + e];
                unsigned short h = f2bf(v);
                WpH[y] = h; WpL[y] = f2bf(v - bf2f(h));
            }
        }
        return;
    }

    // -------- obs-phase bins for t=1..8 --------
    const int seq = blockIdx.x & 31;
    const int tt = (blockIdx.x >> 5) + 1;      // step 1..8
    const int posIdx = (tt <= 7) ? tt : 7;     // bins(8) use obs[7]
    const int lane = tid & 63;
    const int wv = tid >> 6;
    const float gnorm = (float)(2.0 / 7.0);
    const size_t mb = (size_t)(tt * 32 + seq);

    if (tid < 64) posb[tid] = p.obs_abs[posIdx * 2048 + seq * 64 + tid];
    if (tid < 64) jneedS[tid] = 0u;
    __syncthreads();
#pragma unroll
    for (int pp = 0; pp < 2; ++pp) {
        int pr = tid + pp * 512;
        int i = pr >> 5, j = pr & 31;
        float rx = (posb[j * 2]     - posb[i * 2])     / gnorm;
        float ry = (posb[j * 2 + 1] - posb[i * 2 + 1]) / gnorm;
        rx = fminf(fmaxf(rx, -4.f), 4.f);
        ry = fminf(fmaxf(ry, -4.f), 4.f);
        int gx = (int)(rx + 4.f);
        int gy = (int)(ry + 4.f);
        int valid = (gx < 8) && (gy < 8) && (i != j);
        int bin = gy * 8 + gx;
        binTabL[pr] = valid ? (unsigned char)bin : (unsigned char)255;
        if (valid) atomicOr(&jneedS[bin], 1u << j);
    }
    __syncthreads();
    if (wv == 0) {
        bool used = jneedS[lane] != 0u;
        unsigned long long bal = __ballot(used);
        int myIdx = __popcll(bal & ((1ull << lane) - 1ull));
        if (used) p.ulG[mb * 64 + myIdx] = (unsigned char)lane;
        binSlotL[lane] = used ? (unsigned char)myIdx : (unsigned char)255;
        if (lane == 0) p.nUG[mb] = (int)__popcll(bal);
    }
    if (tid < 64) p.jneedG[mb * 64 + tid] = jneedS[tid];
    __syncthreads();
    if (tid < 32) {
        const int i = tid;
        unsigned rw[8];
#pragma unroll
        for (int w = 0; w < 8; ++w)
            rw[w] = *(const unsigned*)&binTabL[i * 32 + w * 4];
        unsigned long long cntp = 0;
#pragma unroll
        for (int j = 0; j < 32; ++j) {
            unsigned bb = (rw[j >> 2] >> ((j & 3) * 8)) & 255u;
            if (bb != 255u) cntp += 1ull << (5 * (binSlotL[bb] >> 3));
        }
        unsigned long long pre = 0; unsigned sum = 0;
#pragma unroll
        for (int c = 0; c < 8; ++c) {
            pre |= (unsigned long long)sum << (5 * c);
            sum += (unsigned)((cntp >> (5 * c)) & 31);
        }
        p.gstartG[mb * 32 + i] = pre | ((unsigned long long)sum << 40);
        unsigned long long pos = pre;
#pragma unroll
        for (int j = 0; j < 32; ++j) {
            unsigned bb = (rw[j >> 2] >> ((j & 3) * 8)) & 255u;
            if (bb != 255u) {
                int sg = binSlotL[bb];
                int c = sg >> 3;
                int pidx = (int)((pos >> (5 * c)) & 31);
                p.glistG[mb * 1024 + i * 32 + pidx] = (unsigned short)((sg << 5) | j);
                pos += 1ull << (5 * c);
            }
        }
    }
}

// ---------------- plain prep (fallback path only) ----------------
__global__ void slstm_prep(const float* __restrict__ Wp,
                           const float* __restrict__ Wi, const float* __restrict__ Wf,
                           const float* __restrict__ Wo, const float* __restrict__ Wg,
                           unsigned short* __restrict__ W4H, unsigned short* __restrict__ W4L,
                           unsigned short* __restrict__ WpH, unsigned short* __restrict__ WpL) {
    int x = blockIdx.x * blockDim.x + threadIdx.x;
    const int NW4 = 32 * 8 * 64 * 8;
    const int NWP = 64 * 4 * 4 * 64 * 8;
    if (x < NW4) {
        int j = x & 7, lane = (x >> 3) & 63, ks = (x >> 9) & 7, nt2 = x >> 12;
        int q = nt2 & 3, wvb = nt2 >> 2;
        int col = wvb * 16 + (lane & 15);
        int k = ks * 32 + ((lane >> 4) << 3) + j;
        const float* W = (q == 0) ? Wi : (q == 1) ? Wf : (q == 2) ? Wo : Wg;
        float v = W[k * 128 + col];
        unsigned short h = f2bf(v);
        W4H[x] = h; W4L[x] = f2bf(v - bf2f(h));
    } else if (x < NW4 + NWP) {
        int y = x - NW4;
        int j = y & 7, lane = (y >> 3) & 63, ks = (y >> 9) & 3, nt = (y >> 11) & 3, bin = y >> 13;
        int e = nt * 16 + (lane & 15);
        int k = ks * 32 + ((lane >> 4) << 3) + j;
        float v = Wp[(bin * 128 + k) * 64 + e];
        unsigned short h = f2bf(v);
        WpH[y] = h; WpL[y] = f2bf(v - bf2f(h));
    }
}

// ---------------- kernel A: social Y-GEMM, 8 WGs x 256 thr per sequence ----------------
// XCD-local: seq = blockIdx&31. Wave unit W = wrole*4+wv in 0..31: slot stride 16, np = W&1.
// Each wave computes BOTH j-halves per (slot,np): Wp frags loaded once. Chains per
// (slot,np,nt,m) identical to prior rounds => bit-identical Y.
__global__ __launch_bounds__(256) void slstm_socialY(SP p, int t) {
    const int seq = blockIdx.x & 31;
    const int wrole = blockIdx.x >> 5;
    const int tid = threadIdx.x, lane = tid & 63, wv = tid >> 6;
    const int W = wrole * 4 + wv;          // 0..31
    const int slotG = W >> 1;              // 0..15
    const int np = W & 1;                  // nt-pair
    const int j4 = (lane >> 4) << 2;
    const unsigned short* hH = p.hBH + (size_t)seq * 4096;
    const unsigned short* hM = p.hBM + (size_t)seq * 4096;
    float* Yb = p.YG + (size_t)seq * 131072;
    const size_t mb = (size_t)(t * 32 + seq);
    const int nU = p.nUG[mb];

    s8v Ah[2][4], Am[2][4];
#pragma unroll
    for (int m = 0; m < 2; ++m)
#pragma unroll
        for (int ks = 0; ks < 4; ++ks) {
            int row = m * 16 + (lane & 15);
            int o = row * 128 + ks * 32 + ((lane >> 4) << 3);
            Ah[m][ks] = *(const s8v*)&hH[o];
            Am[m][ks] = *(const s8v*)&hM[o];
        }
    for (int slot = slotG; slot < nU; slot += 16) {
        int bin = p.ulG[mb * 64 + slot];
        unsigned need = p.jneedG[mb * 64 + bin];
        s8v bh0[4], bl0[4], bh1[4], bl1[4];
#pragma unroll
        for (int ks = 0; ks < 4; ++ks) {
            int foA = ((bin * 4 + np * 2) * 4 + ks) * 64 + lane;
            int foB = ((bin * 4 + np * 2 + 1) * 4 + ks) * 64 + lane;
            bh0[ks] = ((const s8v*)p.WpH)[foA];
            bl0[ks] = ((const s8v*)p.WpL)[foA];
            bh1[ks] = ((const s8v*)p.WpH)[foB];
            bl1[ks] = ((const s8v*)p.WpL)[foB];
        }
#pragma unroll
        for (int m = 0; m < 2; ++m) {
            unsigned hm = (need >> (16 * m)) & 0xFFFFu;
            if (!hm) continue;
            f32x4 a0 = {0.f, 0.f, 0.f, 0.f};
            f32x4 a1 = {0.f, 0.f, 0.f, 0.f};
#pragma unroll
            for (int ks = 0; ks < 4; ++ks) {
                a0 = __builtin_amdgcn_mfma_f32_16x16x32_bf16(Am[m][ks], bh0[ks], a0, 0, 0, 0);
                a0 = __builtin_amdgcn_mfma_f32_16x16x32_bf16(Ah[m][ks], bl0[ks], a0, 0, 0, 0);
                a0 = __builtin_amdgcn_mfma_f32_16x16x32_bf16(Ah[m][ks], bh0[ks], a0, 0, 0, 0);
                a1 = __builtin_amdgcn_mfma_f32_16x16x32_bf16(Am[m][ks], bh1[ks], a1, 0, 0, 0);
                a1 = __builtin_amdgcn_mfma_f32_16x16x32_bf16(Ah[m][ks], bl1[ks], a1, 0, 0, 0);
                a1 = __builtin_amdgcn_mfma_f32_16x16x32_bf16(Ah[m][ks], bh1[ks], a1, 0, 0, 0);
            }
#pragma unroll
            for (int nt = 0; nt < 2; ++nt) {
                int e = (np * 2 + nt) * 16 + (lane & 15);
                const f32x4 a = nt ? a1 : a0;
#pragma unroll
                for (int r = 0; r < 4; ++r) {
                    if ((hm >> (j4 + r)) & 1u) {
                        int j = m * 16 + j4 + r;
                        Yb[(slot * 32 + j) * 64 + e] = a[r];
                    }
                }
            }
        }
    }
}

// ---------------- kernel B: per-step master (gather-first + gates + cell + next-bins) ----------------
__global__ __launch_bounds__(512, 1) void slstm_step(SP p, int t) {
    __shared__ __align__(16) unsigned short combH[32 * 256];
    __shared__ __align__(16) unsigned short combM[32 * 256];
    __shared__ float posb[64];
    __shared__ float pvbuf[64];
    __shared__ float red[256];
    __shared__ unsigned char binTabL[1024];
    __shared__ unsigned char binSlotL[64];
    __shared__ unsigned jneedS[64];
    __shared__ float biasL[512], beL[64], bpL[64], WeL[128], WoutL[256], boutL[2];

    const int seq = blockIdx.x;
    const int tid = threadIdx.x;
    const int lane = tid & 63;
    const int wv = tid >> 6;
    const int gi = tid >> 4;
    const int gg = tid & 15;
    const int hc = wv * 16 + (lane & 15);
    const float gnorm = (float)(2.0 / 7.0);
    const size_t mb = (size_t)(t * 32 + seq);

    // ---------- gather s from Y first (loads overlap everything below) ----------
    float sreg[4] = {0.f, 0.f, 0.f, 0.f};
    if (t > 0) {
        const int e0 = gg * 4;
        const unsigned long long sp = p.gstartG[mb * 32 + gi];
        const int cnt = (int)(sp >> 40);
        const unsigned short* gl = p.glistG + mb * 1024 + gi * 32;
        const float* Yb = p.YG + (size_t)seq * 131072;
        for (int p0 = 0; p0 < cnt; p0 += 4) {
            unsigned long long e4 = *(const unsigned long long*)&gl[p0];
            int n = cnt - p0;
            unsigned en0 = (unsigned)(e4 & 0xFFFF), en1 = (unsigned)((e4 >> 16) & 0xFFFF);
            unsigned en2 = (unsigned)((e4 >> 32) & 0xFFFF), en3 = (unsigned)((e4 >> 48) & 0xFFFF);
            float4 y0, y1, y2, y3;
            if (n > 0) y0 = *(const float4*)&Yb[(((en0 >> 5) * 32) + (en0 & 31)) * 64 + e0];
            if (n > 1) y1 = *(const float4*)&Yb[(((en1 >> 5) * 32) + (en1 & 31)) * 64 + e0];
            if (n > 2) y2 = *(const float4*)&Yb[(((en2 >> 5) * 32) + (en2 & 31)) * 64 + e0];
            if (n > 3) y3 = *(const float4*)&Yb[(((en3 >> 5) * 32) + (en3 & 31)) * 64 + e0];
            if (n > 0) { sreg[0] += y0.x; sreg[1] += y0.y; sreg[2] += y0.z; sreg[3] += y0.w; }
            if (n > 1) { sreg[0] += y1.x; sreg[1] += y1.y; sreg[2] += y1.z; sreg[3] += y1.w; }
            if (n > 2) { sreg[0] += y2.x; sreg[1] += y2.y; sreg[2] += y2.z; sreg[3] += y2.w; }
            if (n > 3) { sreg[0] += y3.x; sreg[1] += y3.y; sreg[2] += y3.z; sreg[3] += y3.w; }
        }
    }

    // constants + h staging (overlaps gather latency)
    biasL[tid] = (tid < 128) ? p.bi[tid] : (tid < 256) ? p.bfv[tid - 128]
               : (tid < 384) ? p.bo[tid - 256] : p.bg[tid - 384];
    if (tid < 64) { beL[tid] = p.be[tid]; bpL[tid] = p.bp[tid]; }
    if (tid < 128) WeL[tid] = p.We[tid];
    if (tid < 256) WoutL[tid] = p.Wout[tid];
    if (tid < 2) boutL[tid] = p.bout[tid];

    if (t > 0) {
        for (int x = tid; x < 4096; x += 512) {
            int row = x >> 7, k = x & 127;
            int ci = row * 256 + ((64 + k) ^ ((row & 7) << 3));
            combH[ci] = p.hBH[seq * 4096 + x];
            combM[ci] = p.hBM[seq * 4096 + x];
        }
    } else {
        for (int x = tid; x < 4096; x += 512) {
            int row = x >> 7, k = x & 127;
            int ci = row * 256 + ((64 + k) ^ ((row & 7) << 3));
            combH[ci] = 0; combM[ci] = 0;
        }
    }

    // finalize s = relu(pooled + bp) -> comb cols 192..255 (disjoint from staging cols)
    {
        int e0 = gg * 4;
#pragma unroll
        for (int r = 0; r < 4; ++r) {
            float v = fmaxf(sreg[r] + bpL[e0 + r], 0.f);   // bpL written by this thread's tid<64? no:
            // NOTE: bpL written above by threads tid<64; this thread may differ -> need barrier? The
            // constants were written without a barrier. Use a barrier before consuming them.
            (void)v;
            break;
        }
    }
    __syncthreads();   // constants + staging + (gather done: register-local) visible
    {
        int e0 = gg * 4;
#pragma unroll
        for (int r = 0; r < 4; ++r) {
            float v = fmaxf(sreg[r] + bpL[e0 + r], 0.f);
            store2(combH, combM, gi * 256 + ((192 + e0 + r) ^ ((gi & 7) << 3)), v);
        }
    }

    // ---------- E phase ----------
    if (t < OBS_T) {
        int e0 = gg * 4;
        float x0 = p.obs_rel[t * 2048 + seq * 64 + gi * 2];
        float x1 = p.obs_rel[t * 2048 + seq * 64 + gi * 2 + 1];
#pragma unroll
        for (int r = 0; r < 4; ++r) {
            int e = e0 + r;
            float v = x0 * WeL[e] + x1 * WeL[64 + e] + beL[e];
            store2(combH, combM, gi * 256 + (e ^ ((gi & 7) << 3)), v);
        }
    } else {
        if (tid < 64) posb[tid] = (t == OBS_T) ? p.obs_abs[7 * 2048 + seq * 64 + tid]
                                               : p.posG[seq * 64 + tid];
        if (tid < 256) {
            int i = tid >> 3, d = (tid >> 2) & 1, pp = tid & 3;
            float acc = 0.f;
            int k0 = pp * 32;
            for (int k = k0; k < k0 + 32; ++k)
                acc += p.hFG[seq * 4096 + i * 128 + k] * WoutL[k * 2 + d];
            red[tid] = acc;
        }
        __syncthreads();
        if (tid < 64) {
            int d = tid & 1;
            float pv = red[tid * 4] + red[tid * 4 + 1] + red[tid * 4 + 2] + red[tid * 4 + 3]
                     + boutL[d];
            p.out[(t - OBS_T) * 2048 + seq * 64 + tid] = pv;
            posb[tid] += pv;
            p.posG[seq * 64 + tid] = posb[tid];
            pvbuf[tid] = pv;
        }
        __syncthreads();
        {
            int e0 = gg * 4;
            float x0 = pvbuf[gi * 2], x1 = pvbuf[gi * 2 + 1];
#pragma unroll
            for (int r = 0; r < 4; ++r) {
                int e = e0 + r;
                float v = x0 * WeL[e] + x1 * WeL[64 + e] + beL[e];
                store2(combH, combM, gi * 256 + (e ^ ((gi & 7) << 3)), v);
            }
        }
    }
    __syncthreads();

    // ---------- gates (bf16x2 MFMA, ks-prefetched) ----------
    f32x4 acc[4][2];
    {
        f32x4 zero = {0.f, 0.f, 0.f, 0.f};
#pragma unroll
        for (int q = 0; q < 4; ++q) { acc[q][0] = zero; acc[q][1] = zero; }
        s8v gbh[2][4], gbl[2][4];
#pragma unroll
        for (int q = 0; q < 4; ++q) {
            int fo = ((wv * 4 + q) * 8 + 0) * 64 + lane;
            gbh[0][q] = ((const s8v*)p.W4H)[fo];
            gbl[0][q] = ((const s8v*)p.W4L)[fo];
        }
#pragma unroll
        for (int ks = 0; ks < 8; ++ks) {
            const int cb = ks & 1;
            if (ks < 7) {
#pragma unroll
                for (int q = 0; q < 4; ++q) {
                    int fo = ((wv * 4 + q) * 8 + ks + 1) * 64 + lane;
                    gbh[cb ^ 1][q] = ((const s8v*)p.W4H)[fo];
                    gbl[cb ^ 1][q] = ((const s8v*)p.W4L)[fo];
                }
            }
            s8v Ah[2], Am[2];
#pragma unroll
            for (int m = 0; m < 2; ++m) {
                int row = m * 16 + (lane & 15);
                int k = ks * 32 + ((lane >> 4) << 3);
                int ci = row * 256 + (k ^ ((row & 7) << 3));
                Ah[m] = *(const s8v*)&combH[ci];
                Am[m] = *(const s8v*)&combM[ci];
            }
#pragma unroll
            for (int q = 0; q < 4; ++q)
#pragma unroll
                for (int m = 0; m < 2; ++m) {
                    acc[q][m] = __builtin_amdgcn_mfma_f32_16x16x32_bf16(Am[m], gbh[cb][q], acc[q][m], 0, 0, 0);
                    acc[q][m] = __builtin_amdgcn_mfma_f32_16x16x32_bf16(Ah[m], gbl[cb][q], acc[q][m], 0, 0, 0);
                    acc[q][m] = __builtin_amdgcn_mfma_f32_16x16x32_bf16(Ah[m], gbh[cb][q], acc[q][m], 0, 0, 0);
                }
        }
    }

    // ---------- cell (global state round-trip) ----------
    {
        float b0 = biasL[hc], b1 = biasL[128 + hc], b2 = biasL[256 + hc], b3 = biasL[384 + hc];
#pragma unroll
        for (int m = 0; m < 2; ++m)
#pragma unroll
            for (int r = 0; r < 4; ++r) {
                int row = m * 16 + ((lane >> 4) << 2) + r;
                int gidx = seq * 4096 + row * 128 + hc;
                float cprev = (t > 0) ? p.cG[gidx] : 0.f;
                float pi = acc[0][m][r] + b0;
                float pf = acc[1][m][r] + b1;
                float po = acc[2][m][r] + b2;
                float pg = acc[3][m][r] + b3;
                float ig = 1.f / (1.f + expf(-pi));
                float fg = 1.f / (1.f + expf(-pf));
                float og = 1.f / (1.f + expf(-po));
                float gv = tanhf(pg);
                float cv = fg * cprev + ig * gv;
                p.cG[gidx] = cv;
                float hv = og * tanhf(cv);
                p.hFG[gidx] = hv;
                unsigned short hh = f2bf(hv);
                float r1 = hv - bf2f(hh);
                p.hBH[gidx] = hh;
                p.hBM[gidx] = f2bf(r1);
            }
    }

    // ---------- tail: bins/glist for step t+1 (pred steps only) ----------
    if (t >= OBS_T && t < NSTEPS - 1) {
        const size_t nb = (size_t)((t + 1) * 32 + seq);
        if (tid < 64) jneedS[tid] = 0u;
        __syncthreads();
#pragma unroll
        for (int pp = 0; pp < 2; ++pp) {
            int pr = tid + pp * 512;
            int i = pr >> 5, j = pr & 31;
            float rx = (posb[j * 2]     - posb[i * 2])     / gnorm;
            float ry = (posb[j * 2 + 1] - posb[i * 2 + 1]) / gnorm;
            rx = fminf(fmaxf(rx, -4.f), 4.f);
            ry = fminf(fmaxf(ry, -4.f), 4.f);
            int gx = (int)(rx + 4.f);
            int gy = (int)(ry + 4.f);
            int valid = (gx < 8) && (gy < 8) && (i != j);
            int bin = gy * 8 + gx;
            binTabL[pr] = valid ? (unsigned char)bin : (unsigned char)255;
            if (valid) atomicOr(&jneedS[bin], 1u << j);
        }
        __syncthreads();
        if (wv == 0) {
            bool used = jneedS[lane] != 0u;
            unsigned long long bal = __ballot(used);
            int myIdx = __popcll(bal & ((1ull << lane) - 1ull));
            if (used) p.ulG[nb * 64 + myIdx] = (unsigned char)lane;
            binSlotL[lane] = used ? (unsigned char)myIdx : (unsigned char)255;
            if (lane == 0) p.nUG[nb] = (int)__popcll(bal);
        }
        if (tid < 64) p.jneedG[nb * 64 + tid] = jneedS[tid];
        __syncthreads();
        if (tid < 32) {
            const int i = tid;
            unsigned rw[8];
#pragma unroll
            for (int w = 0; w < 8; ++w)
                rw[w] = *(const unsigned*)&binTabL[i * 32 + w * 4];
            unsigned long long cntp = 0;
#pragma unroll
            for (int j = 0; j < 32; ++j) {
                unsigned bb = (rw[j >> 2] >> ((j & 3) * 8)) & 255u;
                if (bb != 255u) cntp += 1ull << (5 * (binSlotL[bb] >> 3));
            }
            unsigned long long pre = 0; unsigned sum = 0;
#pragma unroll
            for (int c = 0; c < 8; ++c) {
                pre |= (unsigned long long)sum << (5 * c);
                sum += (unsigned)((cntp >> (5 * c)) & 31);
            }
            p.gstartG[nb * 32 + i] = pre | ((unsigned long long)sum << 40);
            unsigned long long pos = pre;
#pragma unroll
            for (int j = 0; j < 32; ++j) {
                unsigned bb = (rw[j >> 2] >> ((j & 3) * 8)) & 255u;
                if (bb != 255u) {
                    int sg = binSlotL[bb];
                    int c = sg >> 3;
                    int pidx = (int)((pos >> (5 * c)) & 31);
                    p.glistG[nb * 1024 + i * 32 + pidx] = (unsigned short)((sg << 5) | j);
                    pos += 1ull << (5 * c);
                }
            }
        }
    }
}

// ---------------- fallback: round-7 single-WG kernel (verbatim) ----------------
__global__ __launch_bounds__(512, 1) void slstm_main_fb(
    const float* __restrict__ obs_rel, const float* __restrict__ obs_abs,
    const float* __restrict__ We, const float* __restrict__ be,
    const float* __restrict__ bp,
    const float* __restrict__ bi, const float* __restrict__ bfv,
    const float* __restrict__ bo, const float* __restrict__ bg,
    const float* __restrict__ Wout, const float* __restrict__ bout,
    const unsigned short* __restrict__ W4H, const unsigned short* __restrict__ W4L,
    const unsigned short* __restrict__ WpH, const unsigned short* __restrict__ WpL,
    float* __restrict__ out) {

    __shared__ __align__(16) unsigned short combH[32 * 256];
    __shared__ __align__(16) unsigned short combM[32 * 256];
    __shared__ __align__(16) float hbuf[32 * 128];
    __shared__ __align__(16) float scratch[32 * 512];
    __shared__ float posb[64];
    __shared__ float pvbuf[64];
    __shared__ float red[256];
    __shared__ unsigned char binTab[1024];
    __shared__ unsigned char usedList[64];
    __shared__ unsigned char binSlotG[64];
    __shared__ unsigned short glist[1024];
    __shared__ unsigned long long gstartPacked[32];
    __shared__ int nUsedS;
    __shared__ unsigned usedMask[2];
    __shared__ unsigned jm[4];
    __shared__ float biasL[512], beL[64], bpL[64], WeL[128], WoutL[256], boutL[2];

    const int tid = threadIdx.x;
    const int lane = tid & 63;
    const int wv = tid >> 6;
    const int b = blockIdx.x;

    if (tid < 512) biasL[tid] = (tid < 128) ? bi[tid] : (tid < 256) ? bfv[tid - 128]
                              : (tid < 384) ? bo[tid - 256] : bg[tid - 384];
    if (tid < 64) { beL[tid] = be[tid]; bpL[tid] = bp[tid]; }
    if (tid < 128) WeL[tid] = We[tid];
    if (tid < 256) WoutL[tid] = Wout[tid];
    if (tid < 2) boutL[tid] = bout[tid];
    for (int x = tid; x < 32 * 256; x += 512) { combH[x] = 0; combM[x] = 0; }
    for (int x = tid; x < 32 * 128; x += 512) hbuf[x] = 0.f;
    float creg[8];
#pragma unroll
    for (int r = 0; r < 8; ++r) creg[r] = 0.f;
    __syncthreads();

    const float gnorm = (float)(2.0 / 7.0);
    const int gi = tid >> 4;
    const int gg = tid & 15;
    const int hc = wv * 16 + (lane & 15);

    for (int t = 0; t < NSTEPS; ++t) {
        if (t < OBS_T) {
            if (tid < 64) posb[tid] = obs_abs[t * 2048 + b * 64 + tid];
            {
                int e0 = gg * 4;
                float x0 = obs_rel[t * 2048 + b * 64 + gi * 2];
                float x1 = obs_rel[t * 2048 + b * 64 + gi * 2 + 1];
#pragma unroll
                for (int r = 0; r < 4; ++r) {
                    int e = e0 + r;
                    float v = x0 * WeL[e] + x1 * WeL[64 + e] + beL[e];
                    store2(combH, combM, gi * 256 + (e ^ ((gi & 7) << 3)), v);
                }
            }
        }
        if (tid < 2) usedMask[tid] = 0u;
        if (tid < 4) jm[tid] = 0u;
        __syncthreads();

        float sreg[4] = {0.f, 0.f, 0.f, 0.f};
        if (t > 0) {
#pragma unroll
            for (int pp = 0; pp < 2; ++pp) {
                int p = tid + pp * 512;
                int i = p >> 5, j = p & 31;
                float rx = (posb[j * 2]     - posb[i * 2])     / gnorm;
                float ry = (posb[j * 2 + 1] - posb[i * 2 + 1]) / gnorm;
                rx = fminf(fmaxf(rx, -4.f), 4.f);
                ry = fminf(fmaxf(ry, -4.f), 4.f);
                int gx = (int)(rx + 4.f);
                int gy = (int)(ry + 4.f);
                int valid = (gx < 8) && (gy < 8) && (i != j);
                int bin = gy * 8 + gx;
                binTab[p] = valid ? (unsigned char)bin : (unsigned char)255;
                if (valid) {
                    atomicOr(&usedMask[bin >> 5], 1u << (bin & 31));
                    atomicOr(&jm[((j < 16) ? 0 : 2) + (bin >> 5)], 1u << (bin & 31));
                }
            }
            __syncthreads();
            if (wv == 0) {
                bool used = (usedMask[lane >> 5] >> (lane & 31)) & 1u;
                unsigned long long bal = __ballot(used);
                int myIdx = __popcll(bal & ((1ull << lane) - 1ull));
                if (used) { usedList[myIdx] = (unsigned char)lane; }
                binSlotG[lane] = used ? (unsigned char)myIdx : (unsigned char)255;
                if (lane == 0) nUsedS = __popcll(bal);
            }
            __syncthreads();
            const int nUsed = nUsedS;
            const int nChunks = (nUsed + 7) >> 3;

            s8v Ahs[2][4], Ams[2][4];
#pragma unroll
            for (int m = 0; m < 2; ++m)
#pragma unroll
                for (int ks = 0; ks < 4; ++ks) {
                    int row = m * 16 + (lane & 15);
                    int k = ks * 32 + ((lane >> 4) << 3);
                    int ci = row * 256 + ((64 + k) ^ ((row & 7) << 3));
                    Ahs[m][ks] = *(const s8v*)&combH[ci];
                    Ams[m][ks] = *(const s8v*)&combM[ci];
                }

            if (tid < 32) {
                const int i = tid;
                unsigned rw[8];
#pragma unroll
                for (int w = 0; w < 8; ++w)
                    rw[w] = *(const unsigned*)&binTab[i * 32 + w * 4];
                unsigned long long cntp = 0;
#pragma unroll
                for (int j = 0; j < 32; ++j) {
                    unsigned bb = (rw[j >> 2] >> ((j & 3) * 8)) & 255u;
                    if (bb != 255u) cntp += 1ull << (5 * (binSlotG[bb] >> 3));
                }
                unsigned long long pre = 0; unsigned sum = 0;
#pragma unroll
                for (int c = 0; c < 8; ++c) {
                    pre |= (unsigned long long)sum << (5 * c);
                    sum += (unsigned)((cntp >> (5 * c)) & 31);
                }
                gstartPacked[i] = pre | ((unsigned long long)sum << 40);
                unsigned long long pos = pre;
#pragma unroll
                for (int j = 0; j < 32; ++j) {
                    unsigned bb = (rw[j >> 2] >> ((j & 3) * 8)) & 255u;
                    if (bb != 255u) {
                        int sg = binSlotG[bb];
                        int c = sg >> 3;
                        int p = (int)((pos >> (5 * c)) & 31);
                        glist[i * 32 + p] = (unsigned short)((sg << 5) | j);
                        pos += 1ull << (5 * c);
                    }
                }
            }

            unsigned long long spReg = 0;
            for (int c = 0; c < nChunks; ++c) {
                int idx = c * 8 + wv;
                if (idx < nUsed) {
                    int bin = usedList[idx];
                    const bool do0 = (jm[bin >> 5]       >> (bin & 31)) & 1;
                    const bool do1 = (jm[2 + (bin >> 5)] >> (bin & 31)) & 1;
#pragma unroll
                    for (int np = 0; np < 2; ++np) {
                        s8v bh0[4], bl0[4], bh1[4], bl1[4];
#pragma unroll
                        for (int ks = 0; ks < 4; ++ks) {
                            int foA = ((bin * 4 + np * 2)     * 4 + ks) * 64 + lane;
                            int foB = ((bin * 4 + np * 2 + 1) * 4 + ks) * 64 + lane;
                            bh0[ks] = ((const s8v*)WpH)[foA];
                            bl0[ks] = ((const s8v*)WpL)[foA];
                            bh1[ks] = ((const s8v*)WpH)[foB];
                            bl1[ks] = ((const s8v*)WpL)[foB];
                        }
                        if (do0) {
                            f32x4 a0 = {0.f, 0.f, 0.f, 0.f};
                            f32x4 a1 = {0.f, 0.f, 0.f, 0.f};
#pragma unroll
                            for (int ks = 0; ks < 4; ++ks) {
                                a0 = __builtin_amdgcn_mfma_f32_16x16x32_bf16(Ams[0][ks], bh0[ks], a0, 0, 0, 0);
                                a0 = __builtin_amdgcn_mfma_f32_16x16x32_bf16(Ahs[0][ks], bl0[ks], a0, 0, 0, 0);
                                a0 = __builtin_amdgcn_mfma_f32_16x16x32_bf16(Ahs[0][ks], bh0[ks], a0, 0, 0, 0);
                                a1 = __builtin_amdgcn_mfma_f32_16x16x32_bf16(Ams[0][ks], bh1[ks], a1, 0, 0, 0);
                                a1 = __builtin_amdgcn_mfma_f32_16x16x32_bf16(Ahs[0][ks], bl1[ks], a1, 0, 0, 0);
                                a1 = __builtin_amdgcn_mfma_f32_16x16x32_bf16(Ahs[0][ks], bh1[ks], a1, 0, 0, 0);
                            }
#pragma unroll
                            for (int nt = 0; nt < 2; ++nt) {
                                int e = (np * 2 + nt) * 16 + (lane & 15);
                                const f32x4 a = nt ? a1 : a0;
#pragma unroll
                                for (int r = 0; r < 4; ++r) {
                                    int j = ((lane >> 4) << 2) + r;
                                    scratch[j * 512 + wv * 64 + (e ^ (((j >> 2) & 3) << 4))] = a[r];
                                }
                            }
                        }
                        if (do1) {
                            f32x4 a0 = {0.f, 0.f, 0.f, 0.f};
                            f32x4 a1 = {0.f, 0.f, 0.f, 0.f};
#pragma unroll
                            for (int ks = 0; ks < 4; ++ks) {
                                a0 = __builtin_amdgcn_mfma_f32_16x16x32_bf16(Ams[1][ks], bh0[ks], a0, 0, 0, 0);
                                a0 = __builtin_amdgcn_mfma_f32_16x16x32_bf16(Ahs[1][ks], bl0[ks], a0, 0, 0, 0);
                                a0 = __builtin_amdgcn_mfma_f32_16x16x32_bf16(Ahs[1][ks], bh0[ks], a0, 0, 0, 0);
                                a1 = __builtin_amdgcn_mfma_f32_16x16x32_bf16(Ams[1][ks], bh1[ks], a1, 0, 0, 0);
                                a1 = __builtin_amdgcn_mfma_f32_16x16x32_bf16(Ahs[1][ks], bl1[ks], a1, 0, 0, 0);
                                a1 = __builtin_amdgcn_mfma_f32_16x16x32_bf16(Ahs[1][ks], bh1[ks], a1, 0, 0, 0);
                            }
#pragma unroll
                            for (int nt = 0; nt < 2; ++nt) {
                                int e = (np * 2 + nt) * 16 + (lane & 15);
                                const f32x4 a = nt ? a1 : a0;
#pragma unroll
                                for (int r = 0; r < 4; ++r) {
                                    int j = 16 + ((lane >> 4) << 2) + r;
                                    scratch[j * 512 + wv * 64 + (e ^ (((j >> 2) & 3) << 4))] = a[r];
                                }
                            }
                        }
                    }
                }
                __syncthreads();
                {
                    const int e0 = gg * 4;
                    if (c == 0) spReg = gstartPacked[gi];
                    int p0 = (int)((spReg >> (5 * c)) & 31);
                    int p1 = (int)((spReg >> (5 * c + 5)) & 31);
                    for (int p = p0; p < p1; ++p) {
                        unsigned en = glist[gi * 32 + p];
                        int slot = (en >> 5) & 7;
                        int j = en & 31;
                        const float4 y = *(const float4*)
                            &scratch[j * 512 + slot * 64 + (e0 ^ (((j >> 2) & 3) << 4))];
                        sreg[0] += y.x; sreg[1] += y.y; sreg[2] += y.z; sreg[3] += y.w;
                    }
                }
                __syncthreads();
            }
        }
        {
            int e0 = gg * 4;
#pragma unroll
            for (int r = 0; r < 4; ++r) {
                float v = fmaxf(sreg[r] + bpL[e0 + r], 0.f);
                store2(combH, combM, gi * 256 + ((192 + e0 + r) ^ ((gi & 7) << 3)), v);
            }
        }
        if (t >= OBS_T) {
            if (tid < 256) {
                int i = tid >> 3, d = (tid >> 2) & 1, pp = tid & 3;
                float acc = 0.f;
                int k0 = pp * 32;
                for (int k = k0; k < k0 + 32; ++k)
                    acc += hbuf[i * 128 + (k ^ ((i & 7) << 2))] * WoutL[k * 2 + d];
                red[tid] = acc;
            }
            __syncthreads();
            if (tid < 64) {
                int d = tid & 1;
                float pv = red[tid * 4] + red[tid * 4 + 1] + red[tid * 4 + 2] + red[tid * 4 + 3]
                         + boutL[d];
                out[(t - OBS_T) * 2048 + b * 64 + tid] = pv;
                posb[tid] += pv;
                pvbuf[tid] = pv;
            }
            __syncthreads();
            {
                int e0 = gg * 4;
                float x0 = pvbuf[gi * 2], x1 = pvbuf[gi * 2 + 1];
#pragma unroll
                for (int r = 0; r < 4; ++r) {
                    int e = e0 + r;
                    float v = x0 * WeL[e] + x1 * WeL[64 + e] + beL[e];
                    store2(combH, combM, gi * 256 + (e ^ ((gi & 7) << 3)), v);
                }
            }
        }
        __syncthreads();
        {
            f32x4 acc[4][2];
            f32x4 zero = {0.f, 0.f, 0.f, 0.f};
#pragma unroll
            for (int q = 0; q < 4; ++q) { acc[q][0] = zero; acc[q][1] = zero; }
            s8v gbh[2][4], gbl[2][4];
#pragma unroll
            for (int q = 0; q < 4; ++q) {
                int fo = ((wv * 4 + q) * 8 + 0) * 64 + lane;
                gbh[0][q] = ((const s8v*)W4H)[fo];
                gbl[0][q] = ((const s8v*)W4L)[fo];
            }
#pragma unroll
            for (int ks = 0; ks < 8; ++ks) {
                const int cb = ks & 1;
                if (ks < 7) {
#pragma unroll
                    for (int q = 0; q < 4; ++q) {
                        int fo = ((wv * 4 + q) * 8 + ks + 1) * 64 + lane;
                        gbh[cb ^ 1][q] = ((const s8v*)W4H)[fo];
                        gbl[cb ^ 1][q] = ((const s8v*)W4L)[fo];
                    }
                }
                s8v Ah[2], Am[2];
#pragma unroll
                for (int m = 0; m < 2; ++m) {
                    int row = m * 16 + (lane & 15);
                    int k = ks * 32 + ((lane >> 4) << 3);
                    int ci = row * 256 + (k ^ ((row & 7) << 3));
                    Ah[m] = *(const s8v*)&combH[ci];
                    Am[m] = *(const s8v*)&combM[ci];
                }
#pragma unroll
                for (int q = 0; q < 4; ++q)
#pragma unroll
                    for (int m = 0; m < 2; ++m) {
                        acc[q][m] = __builtin_amdgcn_mfma_f32_16x16x32_bf16(Am[m], gbh[cb][q], acc[q][m], 0, 0, 0);
                        acc[q][m] = __builtin_amdgcn_mfma_f32_16x16x32_bf16(Ah[m], gbl[cb][q], acc[q][m], 0, 0, 0);
                        acc[q][m] = __builtin_amdgcn_mfma_f32_16x16x32_bf16(Ah[m], gbh[cb][q], acc[q][m], 0, 0, 0);
                    }
            }
            __syncthreads();
            float b0 = biasL[hc], b1 = biasL[128 + hc], b2 = biasL[256 + hc], b3 = biasL[384 + hc];
#pragma unroll
            for (int m = 0; m < 2; ++m)
#pragma unroll
                for (int r = 0; r < 4; ++r) {
                    int s = m * 4 + r;
                    int row = m * 16 + ((lane >> 4) << 2) + r;
                    float pi = acc[0][m][r] + b0;
                    float pf = acc[1][m][r] + b1;
                    float po = acc[2][m][r] + b2;
                    float pg = acc[3][m][r] + b3;
                    float ig = 1.f / (1.f + expf(-pi));
                    float fg = 1.f / (1.f + expf(-pf));
                    float og = 1.f / (1.f + expf(-po));
                    float gv = tanhf(pg);
                    float cv = fg * creg[s] + ig * gv;
                    creg[s] = cv;
                    float hv = og * tanhf(cv);
                    hbuf[row * 128 + (hc ^ ((row & 7) << 2))] = hv;
                    store2(combH, combM, row * 256 + ((64 + hc) ^ ((row & 7) << 3)), hv);
                }
        }
        __syncthreads();
    }
}

extern "C" void kernel_launch(void* const* d_in, const int* in_sizes, int n_in,
                              void* d_out, int out_size, void* d_ws, size_t ws_size,
                              hipStream_t stream) {
    const float* obs_rel = (const float*)d_in[0];
    const float* obs_abs = (const float*)d_in[1];
    const float* We   = (const float*)d_in[3];
    const float* be   = (const float*)d_in[4];
    const float* Wp   = (const float*)d_in[5];
    const float* bp   = (const float*)d_in[6];
    const float* Wi   = (const float*)d_in[7];
    const float* bi   = (const float*)d_in[8];
    const float* Wf   = (const float*)d_in[9];
    const float* bf   = (const float*)d_in[10];
    const float* Wo   = (const float*)d_in[11];
    const float* bo   = (const float*)d_in[12];
    const float* Wg   = (const float*)d_in[13];
    const float* bg   = (const float*)d_in[14];
    const float* Wout = (const float*)d_in[15];
    const float* bout = (const float*)d_in[16];

    char* ws = (char*)d_ws;
    unsigned short* W4H = (unsigned short*)(ws + 0);
    unsigned short* W4L = (unsigned short*)(ws + 262144);
    unsigned short* WpH = (unsigned short*)(ws + 524288);
    unsigned short* WpL = (unsigned short*)(ws + 1572864);
    unsigned short* hBH = (unsigned short*)(ws + 2621440);
    unsigned short* hBM = (unsigned short*)(ws + 2883584);
    float* hFG          = (float*)(ws + 3145728);
    float* cG           = (float*)(ws + 3670016);
    float* posG         = (float*)(ws + 4194304);
    unsigned char* ulG  = (unsigned char*)(ws + 4202496);
    unsigned* jneedG    = (unsigned*)(ws + 4243456);
    int* nUG            = (int*)(ws + 4407296);
    unsigned long long* gstartG = (unsigned long long*)(ws + 4409856);
    unsigned short* glistG = (unsigned short*)(ws + 4573696);
    float* YG           = (float*)(ws + 5884416);
    const size_t NEED   = 22661632;

    if (ws_size >= NEED) {
        SP p;
        p.obs_rel = obs_rel; p.obs_abs = obs_abs; p.We = We; p.be = be; p.bp = bp;
        p.bi = bi; p.bfv = bf; p.bo = bo; p.bg = bg; p.Wout = Wout; p.bout = bout;
        p.W4H = W4H; p.W4L = W4L; p.WpH = WpH; p.WpL = WpL;
        p.hBH = hBH; p.hBM = hBM; p.hFG = hFG; p.cG = cG; p.posG = posG;
        p.ulG = ulG; p.jneedG = jneedG; p.nUG = nUG;
        p.glistG = glistG; p.gstartG = gstartG; p.YG = YG; p.out = (float*)d_out;

        slstm_pre<<<576, 512, 0, stream>>>(p, Wp, Wi, Wf, Wo, Wg, W4H, W4L, WpH, WpL);
        slstm_step<<<32, 512, 0, stream>>>(p, 0);
        for (int t = 1; t < NSTEPS; ++t) {
            slstm_socialY<<<256, 256, 0, stream>>>(p, t);
            slstm_step<<<32, 512, 0, stream>>>(p, t);
        }
    } else {
        slstm_prep<<<2560, 256, 0, stream>>>(Wp, Wi, Wf, Wo, Wg, W4H, W4L, WpH, WpL);
        slstm_main_fb<<<32, 512, 0, stream>>>(obs_rel, obs_abs, We, be, bp, bi, bf, bo, bg,
                                              Wout, bout, W4H, W4L, WpH, WpL,
                                              (float*)d_out);
    }
}